// Round 1
// baseline (2125.175 us; speedup 1.0000x reference)
//
#include <hip/hip_runtime.h>
#include <math.h>

#define B   8
#define L   4096
#define H   256
#define N2  32
#define NL  4
#define O2  512   // 2H
#define TL  32    // gemm l-tile

// ---------------- precompute per-(layer,h,n) params: w = exp(dt*A), cm2 = 2*C*(w-1)/A ----------------
__global__ __launch_bounds__(256) void k_prm(
    const float* __restrict__ log_dt, const float* __restrict__ log_Ar,
    const float* __restrict__ A_im, const float* __restrict__ C_re,
    const float* __restrict__ C_im, float4* __restrict__ prm)
{
    int idx = blockIdx.x * 256 + threadIdx.x;     // NL*H*N2 = 32768
    if (idx >= NL * H * N2) return;
    int layer = idx / (H * N2);
    int rem = idx - layer * (H * N2);
    int h = rem / N2;
    double dt = exp((double)log_dt[layer * H + h]);
    double Ar = -exp((double)log_Ar[idx]);
    double Ai = (double)A_im[idx];
    double dtr = dt * Ar, dti = dt * Ai;
    double er = exp(dtr);
    double wr = er * cos(dti), wi = er * sin(dti);
    double numr = wr - 1.0, numi = wi;
    double den = Ar * Ar + Ai * Ai;
    double qr = (numr * Ar + numi * Ai) / den;
    double qi = (numi * Ar - numr * Ai) / den;
    double cr = (double)C_re[idx], ci = (double)C_im[idx];
    double cmr = cr * qr - ci * qi;
    double cmi = cr * qi + ci * qr;
    prm[idx] = make_float4((float)wr, (float)wi, (float)(2.0 * cmr), (float)(2.0 * cmi));
}

// ---------------- transposes (32x32 LDS tiles) ----------------
__global__ __launch_bounds__(256) void k_tr_xu(const float* __restrict__ x, float* __restrict__ u)
{
    __shared__ float t[32][33];
    int b = blockIdx.z;
    int h0 = blockIdx.x * 32, l0 = blockIdx.y * 32;
    int tx = threadIdx.x & 31, ty = threadIdx.x >> 5;   // ty 0..7
    const float* xb = x + (size_t)b * L * H;
    float* ub = u + (size_t)b * H * L;
#pragma unroll
    for (int i = 0; i < 4; ++i)
        t[ty + i * 8][tx] = xb[(size_t)(l0 + ty + i * 8) * H + h0 + tx];
    __syncthreads();
#pragma unroll
    for (int i = 0; i < 4; ++i)
        ub[(size_t)(h0 + ty + i * 8) * L + l0 + tx] = t[tx][ty + i * 8];
}

__global__ __launch_bounds__(256) void k_tr_uo(const float* __restrict__ u, float* __restrict__ o)
{
    __shared__ float t[32][33];
    int b = blockIdx.z;
    int h0 = blockIdx.x * 32, l0 = blockIdx.y * 32;
    int tx = threadIdx.x & 31, ty = threadIdx.x >> 5;
    const float* ub = u + (size_t)b * H * L;
    float* ob = o + (size_t)b * L * H;
#pragma unroll
    for (int i = 0; i < 4; ++i)
        t[ty + i * 8][tx] = ub[(size_t)(h0 + ty + i * 8) * L + l0 + tx];
    __syncthreads();
#pragma unroll
    for (int i = 0; i < 4; ++i)
        ob[(size_t)(l0 + ty + i * 8) * H + h0 + tx] = t[tx][ty + i * 8];
}

// Wout (NL,512,256) -> Wt (NL,256,512)
__global__ __launch_bounds__(256) void k_tr_w(const float* __restrict__ w, float* __restrict__ wt)
{
    __shared__ float t[32][33];
    int z = blockIdx.z;
    int o0 = blockIdx.x * 32, h0 = blockIdx.y * 32;
    int tx = threadIdx.x & 31, ty = threadIdx.x >> 5;
    const float* ws = w + (size_t)z * O2 * H;
    float* wd = wt + (size_t)z * H * O2;
#pragma unroll
    for (int i = 0; i < 4; ++i)
        t[ty + i * 8][tx] = ws[(size_t)(o0 + ty + i * 8) * H + h0 + tx];
    __syncthreads();
#pragma unroll
    for (int i = 0; i < 4; ++i)
        wd[(size_t)(h0 + ty + i * 8) * O2 + o0 + tx] = t[tx][ty + i * 8];
}

// ---------------- S4D scan: u(B*H,L) -> y = gelu(conv + D*u) ----------------
__device__ __forceinline__ float gelu_f(float x)
{
    return 0.5f * x * (1.0f + erff(x * 0.70710678118654752f));
}

__global__ __launch_bounds__(64) void k_scan(
    const float* __restrict__ u, const float4* __restrict__ prm,
    const float* __restrict__ Dv, float* __restrict__ y)
{
    const int lane = threadIdx.x;
    const int half = lane >> 5;
    const int n = lane & 31;
    const int bhA = blockIdx.x * 2;
    const int bh = bhA + half;
    const int h = bh & (H - 1);
    const float4 p = prm[h * N2 + n];
    const float wr = p.x, wi = p.y, cr = p.z, ci = p.w;
    const float Dh = Dv[h];
    const float* __restrict__ uA = u + (size_t)bhA * L;
    const float* __restrict__ uB = uA + L;
    float* __restrict__ yrow = y + (size_t)bh * L;
    __shared__ float ub[2][64];
    float sr = 0.f, si = 0.f;
    for (int l0 = 0; l0 < L; l0 += 64) {
        __syncthreads();
        float va = uA[l0 + lane];
        float vb = uB[l0 + lane];
        ub[0][lane] = va;
        ub[1][lane] = vb;
        __syncthreads();
        float y0 = 0.f, y1 = 0.f;
#pragma unroll
        for (int j = 0; j < 64; ++j) {
            float uv = ub[half][j];
            float nsr = fmaf(wr, sr, fmaf(-wi, si, uv));
            float nsi = fmaf(wr, si, wi * sr);
            sr = nsr; si = nsi;
            float pp = fmaf(cr, sr, -(ci * si));
            pp += __shfl_xor(pp, 16);
            pp += __shfl_xor(pp, 8);
            pp += __shfl_xor(pp, 4);
            pp += __shfl_xor(pp, 2);
            pp += __shfl_xor(pp, 1);
            if ((j & 31) == n) { if (j < 32) y0 = pp; else y1 = pp; }
        }
        float uu0 = ub[half][n];
        float uu1 = ub[half][n + 32];
        yrow[l0 + n]      = gelu_f(fmaf(Dh, uu0, y0));
        yrow[l0 + n + 32] = gelu_f(fmaf(Dh, uu1, y1));
    }
}

// ---------------- fused GEMM(512x256 @ 256xTL) + GLU + residual + channel-LN (in-place u) ----------------
__global__ __launch_bounds__(256) void k_gemm(
    const float* __restrict__ y, float* __restrict__ u,
    const float* __restrict__ Wt, const float* __restrict__ bo,
    const float* __restrict__ lng, const float* __restrict__ lnb)
{
    __shared__ float yT[256 * TL];     // [k][c]   32 KB
    __shared__ float wS[16 * O2];      // [kk][o]  32 KB; reused as u tile [h][c]
    __shared__ float red[2 * 32 * 32]; //          8 KB
    __shared__ float mcol[TL], icol[TL];

    const int t = threadIdx.x;
    const int r = t >> 3;      // 0..31 : rows r*8..r*8+7 (and +256)
    const int cg = t & 7;      // 0..7  : cols cg*4..cg*4+3
    const int bid = blockIdx.x;
    const int b = bid >> 7;                // L/TL = 128 tiles per batch
    const int l0 = (bid & 127) * TL;

    // stage y tile [256 x 32]
    {
        const float* ybase = y + (size_t)(b * H) * L + l0;
#pragma unroll
        for (int q = 0; q < 8; ++q) {
            int k = r + q * 32;
            float4 v = *(const float4*)(ybase + (size_t)k * L + cg * 4);
            *(float4*)&yT[k * TL + cg * 4] = v;
        }
    }

    float acc[16][4];
#pragma unroll
    for (int i = 0; i < 8; ++i) {
        float ba = bo[r * 8 + i];
        float bb = bo[256 + r * 8 + i];
#pragma unroll
        for (int j = 0; j < 4; ++j) { acc[i][j] = ba; acc[8 + i][j] = bb; }
    }

    for (int kt = 0; kt < 16; ++kt) {
        __syncthreads();
        {   // stage 16 x 512 W tile (already k-major in Wt)
            int kk = t >> 4;         // 0..15
            int oc = t & 15;         // 0..15
            const float* wrow = Wt + (size_t)(kt * 16 + kk) * O2;
#pragma unroll
            for (int q = 0; q < 8; ++q) {
                int o = oc * 4 + q * 64;
                *(float4*)&wS[kk * O2 + o] = *(const float4*)(wrow + o);
            }
        }
        __syncthreads();
#pragma unroll
        for (int kk = 0; kk < 16; ++kk) {
            float4 yv = *(const float4*)&yT[(kt * 16 + kk) * TL + cg * 4];
            const float* wrow = &wS[kk * O2 + r * 8];
            float4 wa0 = *(const float4*)(wrow);
            float4 wa1 = *(const float4*)(wrow + 4);
            float4 wb0 = *(const float4*)(wrow + 256);
            float4 wb1 = *(const float4*)(wrow + 260);
            float ya[4] = { yv.x, yv.y, yv.z, yv.w };
            float wa[8] = { wa0.x, wa0.y, wa0.z, wa0.w, wa1.x, wa1.y, wa1.z, wa1.w };
            float wb[8] = { wb0.x, wb0.y, wb0.z, wb0.w, wb1.x, wb1.y, wb1.z, wb1.w };
#pragma unroll
            for (int i = 0; i < 8; ++i)
#pragma unroll
                for (int j = 0; j < 4; ++j) {
                    acc[i][j]     = fmaf(wa[i], ya[j], acc[i][j]);
                    acc[8 + i][j] = fmaf(wb[i], ya[j], acc[8 + i][j]);
                }
        }
    }

    __syncthreads();
    {   // stage u tile into wS as [h][c]
        const float* ubase = u + (size_t)(b * H) * L + l0;
#pragma unroll
        for (int q = 0; q < 8; ++q) {
            int k = r + q * 32;
            float4 v = *(const float4*)(ubase + (size_t)k * L + cg * 4);
            *(float4*)&wS[k * TL + cg * 4] = v;
        }
    }
    __syncthreads();

    float psum[4] = {0.f, 0.f, 0.f, 0.f}, psq[4] = {0.f, 0.f, 0.f, 0.f};
#pragma unroll
    for (int i = 0; i < 8; ++i) {
        int hrow = r * 8 + i;
#pragma unroll
        for (int j = 0; j < 4; ++j) {
            float a = acc[i][j];
            float g = acc[8 + i][j];
            float gl = a / (1.f + expf(-g));           // a * sigmoid(gate)
            float val = gl + wS[hrow * TL + cg * 4 + j]; // + residual u
            acc[i][j] = val;
            psum[j] += val;
            psq[j] = fmaf(val, val, psq[j]);
        }
    }
#pragma unroll
    for (int j = 0; j < 4; ++j) {
        red[r * 32 + cg * 4 + j]          = psum[j];
        red[(32 + r) * 32 + cg * 4 + j]   = psq[j];
    }
    __syncthreads();
    if (t < TL) {
        float s = 0.f, sq = 0.f;
#pragma unroll
        for (int rr = 0; rr < 32; ++rr) {
            s  += red[rr * 32 + t];
            sq += red[(32 + rr) * 32 + t];
        }
        float m = s * (1.0f / 256.0f);
        float v = sq * (1.0f / 256.0f) - m * m;
        mcol[t] = m;
        icol[t] = rsqrtf(v + 1e-5f);
    }
    __syncthreads();
    {
        float* ubase = u + (size_t)(b * H) * L + l0;
#pragma unroll
        for (int i = 0; i < 8; ++i) {
            int hrow = r * 8 + i;
            float g = lng[hrow], bb2 = lnb[hrow];
            float4 ov;
            ov.x = (acc[i][0] - mcol[cg * 4 + 0]) * icol[cg * 4 + 0] * g + bb2;
            ov.y = (acc[i][1] - mcol[cg * 4 + 1]) * icol[cg * 4 + 1] * g + bb2;
            ov.z = (acc[i][2] - mcol[cg * 4 + 2]) * icol[cg * 4 + 2] * g + bb2;
            ov.w = (acc[i][3] - mcol[cg * 4 + 3]) * icol[cg * 4 + 3] * g + bb2;
            *(float4*)(ubase + (size_t)hrow * L + cg * 4) = ov;
        }
    }
}

extern "C" void kernel_launch(void* const* d_in, const int* in_sizes, int n_in,
                              void* d_out, int out_size, void* d_ws, size_t ws_size,
                              hipStream_t stream)
{
    const float* x      = (const float*)d_in[0];
    const float* log_dt = (const float*)d_in[1];
    const float* log_Ar = (const float*)d_in[2];
    const float* A_im   = (const float*)d_in[3];
    const float* C_re   = (const float*)d_in[4];
    const float* C_im   = (const float*)d_in[5];
    const float* Dv     = (const float*)d_in[6];
    const float* Wout   = (const float*)d_in[7];
    const float* bout   = (const float*)d_in[8];
    const float* lng    = (const float*)d_in[9];
    const float* lnb    = (const float*)d_in[10];
    float* out = (float*)d_out;

    float* u   = (float*)d_ws;                        // B*H*L floats (134 MB)
    float* Wt  = u + (size_t)B * H * L;               // NL*H*O2
    float4* prm = (float4*)(Wt + (size_t)NL * H * O2);// NL*H*N2 float4
    float* y = out;                                   // reuse d_out as y scratch

    k_prm<<<(NL * H * N2 + 255) / 256, 256, 0, stream>>>(log_dt, log_Ar, A_im, C_re, C_im, prm);
    k_tr_w<<<dim3(16, 8, NL), 256, 0, stream>>>(Wout, Wt);
    k_tr_xu<<<dim3(8, 128, B), 256, 0, stream>>>(x, u);
    for (int layer = 0; layer < NL; ++layer) {
        k_scan<<<B * H / 2, 64, 0, stream>>>(u, prm + (size_t)layer * H * N2,
                                             Dv + layer * H, y);
        k_gemm<<<B * L / TL, 256, 0, stream>>>(y, u, Wt + (size_t)layer * H * O2,
                                               bout + layer * O2, lng + layer * H, lnb + layer * H);
    }
    k_tr_uo<<<dim3(8, 128, B), 256, 0, stream>>>(u, out);
}

// Round 2
// 1138.339 us; speedup vs baseline: 1.8669x; 1.8669x over previous
//
#include <hip/hip_runtime.h>
#include <math.h>

#define B   8
#define L   4096
#define H   256
#define N2  32
#define NL  4
#define O2  512   // 2H
#define TL  32    // gemm l-tile
#define CCH 8     // scan chunks per row
#define TCH 512   // scan chunk length (L/CCH)

// ---------------- precompute per-(layer,h,n): w = exp(dt*A), cm2 = 2*C*(w-1)/A, wT = w^TCH ----------------
__global__ __launch_bounds__(256) void k_prm(
    const float* __restrict__ log_dt, const float* __restrict__ log_Ar,
    const float* __restrict__ A_im, const float* __restrict__ C_re,
    const float* __restrict__ C_im, float4* __restrict__ prm,
    float2* __restrict__ prmT)
{
    int idx = blockIdx.x * 256 + threadIdx.x;     // NL*H*N2 = 32768
    if (idx >= NL * H * N2) return;
    int layer = idx / (H * N2);
    int rem = idx - layer * (H * N2);
    int h = rem / N2;
    double dt = exp((double)log_dt[layer * H + h]);
    double Ar = -exp((double)log_Ar[idx]);
    double Ai = (double)A_im[idx];
    double dtr = dt * Ar, dti = dt * Ai;
    double er = exp(dtr);
    double wr = er * cos(dti), wi = er * sin(dti);
    double numr = wr - 1.0, numi = wi;
    double den = Ar * Ar + Ai * Ai;
    double qr = (numr * Ar + numi * Ai) / den;
    double qi = (numi * Ar - numr * Ai) / den;
    double cr = (double)C_re[idx], ci = (double)C_im[idx];
    double cmr = cr * qr - ci * qi;
    double cmi = cr * qi + ci * qr;
    prm[idx] = make_float4((float)wr, (float)wi, (float)(2.0 * cmr), (float)(2.0 * cmi));
    double eT = exp(dtr * (double)TCH);
    double aT = dti * (double)TCH;
    prmT[idx] = make_float2((float)(eT * cos(aT)), (float)(eT * sin(aT)));
}

// ---------------- transposes (32x32 LDS tiles) ----------------
__global__ __launch_bounds__(256) void k_tr_xu(const float* __restrict__ x, float* __restrict__ u)
{
    __shared__ float t[32][33];
    int b = blockIdx.z;
    int h0 = blockIdx.x * 32, l0 = blockIdx.y * 32;
    int tx = threadIdx.x & 31, ty = threadIdx.x >> 5;   // ty 0..7
    const float* xb = x + (size_t)b * L * H;
    float* ub = u + (size_t)b * H * L;
#pragma unroll
    for (int i = 0; i < 4; ++i)
        t[ty + i * 8][tx] = xb[(size_t)(l0 + ty + i * 8) * H + h0 + tx];
    __syncthreads();
#pragma unroll
    for (int i = 0; i < 4; ++i)
        ub[(size_t)(h0 + ty + i * 8) * L + l0 + tx] = t[tx][ty + i * 8];
}

__global__ __launch_bounds__(256) void k_tr_uo(const float* __restrict__ u, float* __restrict__ o)
{
    __shared__ float t[32][33];
    int b = blockIdx.z;
    int h0 = blockIdx.x * 32, l0 = blockIdx.y * 32;
    int tx = threadIdx.x & 31, ty = threadIdx.x >> 5;
    const float* ub = u + (size_t)b * H * L;
    float* ob = o + (size_t)b * L * H;
#pragma unroll
    for (int i = 0; i < 4; ++i)
        t[ty + i * 8][tx] = ub[(size_t)(h0 + ty + i * 8) * L + l0 + tx];
    __syncthreads();
#pragma unroll
    for (int i = 0; i < 4; ++i)
        ob[(size_t)(l0 + ty + i * 8) * H + h0 + tx] = t[tx][ty + i * 8];
}

// Wout (NL,512,256) -> Wt (NL,256,512)
__global__ __launch_bounds__(256) void k_tr_w(const float* __restrict__ w, float* __restrict__ wt)
{
    __shared__ float t[32][33];
    int z = blockIdx.z;
    int o0 = blockIdx.x * 32, h0 = blockIdx.y * 32;
    int tx = threadIdx.x & 31, ty = threadIdx.x >> 5;
    const float* ws = w + (size_t)z * O2 * H;
    float* wd = wt + (size_t)z * H * O2;
#pragma unroll
    for (int i = 0; i < 4; ++i)
        t[ty + i * 8][tx] = ws[(size_t)(o0 + ty + i * 8) * H + h0 + tx];
    __syncthreads();
#pragma unroll
    for (int i = 0; i < 4; ++i)
        wd[(size_t)(h0 + ty + i * 8) * O2 + o0 + tx] = t[tx][ty + i * 8];
}

__device__ __forceinline__ float gelu_f(float x)
{
    return 0.5f * x * (1.0f + erff(x * 0.70710678118654752f));
}

// ---------------- scan pass A: per-chunk end states (zero init) ----------------
// block = 64 (1 wave, 2 chunk-rows); __syncthreads() elides to wave-level fence
__global__ __launch_bounds__(64) void k_scanA(
    const float* __restrict__ u, const float4* __restrict__ prm,
    float2* __restrict__ send)
{
    __shared__ float uS[2][64];
    const int t = threadIdx.x;
    const int g = t >> 5, n = t & 31;
    const int id = blockIdx.x * 2 + g;
    const int c = id & (CCH - 1);
    const int bh = id >> 3;               // log2(CCH)=3
    const int h = bh & (H - 1);
    const float4 p = prm[h * N2 + n];
    const float wr = p.x, wi = p.y;
    const float* __restrict__ urow = u + (size_t)bh * L + c * TCH;
    float sr = 0.f, si = 0.f;
    for (int l0 = 0; l0 < TCH; l0 += 64) {
        __syncthreads();
        float2 uv2 = *(const float2*)(urow + l0 + 2 * n);
        uS[g][2 * n]     = uv2.x;
        uS[g][2 * n + 1] = uv2.y;
        __syncthreads();
#pragma unroll
        for (int j = 0; j < 64; ++j) {
            float uv = uS[g][j];
            float nsr = fmaf(wr, sr, fmaf(-wi, si, uv));
            float nsi = fmaf(wr, si, wi * sr);
            sr = nsr; si = nsi;
        }
    }
    send[((size_t)bh * CCH + c) * N2 + n] = make_float2(sr, si);
}

// ---------------- scan pass C: full scan with init states + fused D-skip + GELU ----------------
__global__ __launch_bounds__(64) void k_scanC(
    const float* __restrict__ u, const float4* __restrict__ prm,
    const float2* __restrict__ prmT, const float* __restrict__ Dv,
    const float2* __restrict__ send, float* __restrict__ y)
{
    __shared__ float uS[2][32];
    __shared__ float tile[2][32 * 33];
    const int t = threadIdx.x;
    const int g = t >> 5, n = t & 31;
    const int id = blockIdx.x * 2 + g;
    const int c = id & (CCH - 1);
    const int bh = id >> 3;
    const int h = bh & (H - 1);
    const float4 p = prm[h * N2 + n];
    const float wr = p.x, wi = p.y, cr = p.z, ci = p.w;
    const float Dh = Dv[h];
    const float2 wT = prmT[h * N2 + n];
    const float* __restrict__ urow = u + (size_t)bh * L + c * TCH;
    float* __restrict__ yrow = y + (size_t)bh * L + c * TCH;

    // init state = combine of preceding chunks' end states
    float sr = 0.f, si = 0.f;
    for (int cp = 0; cp < c; ++cp) {
        float2 se = send[((size_t)bh * CCH + cp) * N2 + n];
        float nr = fmaf(wT.x, sr, fmaf(-wT.y, si, se.x));
        float ni = fmaf(wT.x, si, fmaf(wT.y, sr, se.y));
        sr = nr; si = ni;
    }

    float* __restrict__ tg = tile[g];
    for (int l0 = 0; l0 < TCH; l0 += 32) {
        __syncthreads();
        uS[g][n] = urow[l0 + n];
        __syncthreads();
#pragma unroll
        for (int j = 0; j < 32; ++j) {
            float uv = uS[g][j];
            float nsr = fmaf(wr, sr, fmaf(-wi, si, uv));
            float nsi = fmaf(wr, si, wi * sr);
            sr = nsr; si = nsi;
            tg[j * 33 + n] = fmaf(cr, sr, -(ci * si));   // p contribution of state n at step j
        }
        __syncthreads();
        float acc = 0.f;
#pragma unroll
        for (int k = 0; k < 32; ++k) acc += tg[n * 33 + k];   // lane n sums timestep n over states
        yrow[l0 + n] = gelu_f(fmaf(Dh, uS[g][n], acc));
    }
}

// ---------------- fused GEMM(512x256 @ 256xTL) + GLU + residual + channel-LN (in-place u) ----------------
__global__ __launch_bounds__(256) void k_gemm(
    const float* __restrict__ y, float* __restrict__ u,
    const float* __restrict__ Wt, const float* __restrict__ bo,
    const float* __restrict__ lng, const float* __restrict__ lnb)
{
    __shared__ float yT[256 * TL];     // [k][c]   32 KB
    __shared__ float wS[16 * O2];      // [kk][o]  32 KB; reused as u tile [h][c]
    __shared__ float red[2 * 32 * 32]; //          8 KB
    __shared__ float mcol[TL], icol[TL];

    const int t = threadIdx.x;
    const int r = t >> 3;      // 0..31 : rows r*8..r*8+7 (and +256)
    const int cg = t & 7;      // 0..7  : cols cg*4..cg*4+3
    const int bid = blockIdx.x;
    const int b = bid >> 7;                // L/TL = 128 tiles per batch
    const int l0 = (bid & 127) * TL;

    // stage y tile [256 x 32]
    {
        const float* ybase = y + (size_t)(b * H) * L + l0;
#pragma unroll
        for (int q = 0; q < 8; ++q) {
            int k = r + q * 32;
            float4 v = *(const float4*)(ybase + (size_t)k * L + cg * 4);
            *(float4*)&yT[k * TL + cg * 4] = v;
        }
    }

    float acc[16][4];
#pragma unroll
    for (int i = 0; i < 8; ++i) {
        float ba = bo[r * 8 + i];
        float bb = bo[256 + r * 8 + i];
#pragma unroll
        for (int j = 0; j < 4; ++j) { acc[i][j] = ba; acc[8 + i][j] = bb; }
    }

    for (int kt = 0; kt < 16; ++kt) {
        __syncthreads();
        {   // stage 16 x 512 W tile (already k-major in Wt)
            int kk = t >> 4;         // 0..15
            int oc = t & 15;         // 0..15
            const float* wrow = Wt + (size_t)(kt * 16 + kk) * O2;
#pragma unroll
            for (int q = 0; q < 8; ++q) {
                int o = oc * 4 + q * 64;
                *(float4*)&wS[kk * O2 + o] = *(const float4*)(wrow + o);
            }
        }
        __syncthreads();
#pragma unroll
        for (int kk = 0; kk < 16; ++kk) {
            float4 yv = *(const float4*)&yT[(kt * 16 + kk) * TL + cg * 4];
            const float* wrow = &wS[kk * O2 + r * 8];
            float4 wa0 = *(const float4*)(wrow);
            float4 wa1 = *(const float4*)(wrow + 4);
            float4 wb0 = *(const float4*)(wrow + 256);
            float4 wb1 = *(const float4*)(wrow + 260);
            float ya[4] = { yv.x, yv.y, yv.z, yv.w };
            float wa[8] = { wa0.x, wa0.y, wa0.z, wa0.w, wa1.x, wa1.y, wa1.z, wa1.w };
            float wb[8] = { wb0.x, wb0.y, wb0.z, wb0.w, wb1.x, wb1.y, wb1.z, wb1.w };
#pragma unroll
            for (int i = 0; i < 8; ++i)
#pragma unroll
                for (int j = 0; j < 4; ++j) {
                    acc[i][j]     = fmaf(wa[i], ya[j], acc[i][j]);
                    acc[8 + i][j] = fmaf(wb[i], ya[j], acc[8 + i][j]);
                }
        }
    }

    __syncthreads();
    {   // stage u tile into wS as [h][c]
        const float* ubase = u + (size_t)(b * H) * L + l0;
#pragma unroll
        for (int q = 0; q < 8; ++q) {
            int k = r + q * 32;
            float4 v = *(const float4*)(ubase + (size_t)k * L + cg * 4);
            *(float4*)&wS[k * TL + cg * 4] = v;
        }
    }
    __syncthreads();

    float psum[4] = {0.f, 0.f, 0.f, 0.f}, psq[4] = {0.f, 0.f, 0.f, 0.f};
#pragma unroll
    for (int i = 0; i < 8; ++i) {
        int hrow = r * 8 + i;
#pragma unroll
        for (int j = 0; j < 4; ++j) {
            float a = acc[i][j];
            float g = acc[8 + i][j];
            float gl = a / (1.f + expf(-g));           // a * sigmoid(gate)
            float val = gl + wS[hrow * TL + cg * 4 + j]; // + residual u
            acc[i][j] = val;
            psum[j] += val;
            psq[j] = fmaf(val, val, psq[j]);
        }
    }
#pragma unroll
    for (int j = 0; j < 4; ++j) {
        red[r * 32 + cg * 4 + j]          = psum[j];
        red[(32 + r) * 32 + cg * 4 + j]   = psq[j];
    }
    __syncthreads();
    if (t < TL) {
        float s = 0.f, sq = 0.f;
#pragma unroll
        for (int rr = 0; rr < 32; ++rr) {
            s  += red[rr * 32 + t];
            sq += red[(32 + rr) * 32 + t];
        }
        float m = s * (1.0f / 256.0f);
        float v = sq * (1.0f / 256.0f) - m * m;
        mcol[t] = m;
        icol[t] = rsqrtf(v + 1e-5f);
    }
    __syncthreads();
    {
        float* ubase = u + (size_t)(b * H) * L + l0;
#pragma unroll
        for (int i = 0; i < 8; ++i) {
            int hrow = r * 8 + i;
            float g = lng[hrow], bb2 = lnb[hrow];
            float4 ov;
            ov.x = (acc[i][0] - mcol[cg * 4 + 0]) * icol[cg * 4 + 0] * g + bb2;
            ov.y = (acc[i][1] - mcol[cg * 4 + 1]) * icol[cg * 4 + 1] * g + bb2;
            ov.z = (acc[i][2] - mcol[cg * 4 + 2]) * icol[cg * 4 + 2] * g + bb2;
            ov.w = (acc[i][3] - mcol[cg * 4 + 3]) * icol[cg * 4 + 3] * g + bb2;
            *(float4*)(ubase + (size_t)hrow * L + cg * 4) = ov;
        }
    }
}

extern "C" void kernel_launch(void* const* d_in, const int* in_sizes, int n_in,
                              void* d_out, int out_size, void* d_ws, size_t ws_size,
                              hipStream_t stream)
{
    const float* x      = (const float*)d_in[0];
    const float* log_dt = (const float*)d_in[1];
    const float* log_Ar = (const float*)d_in[2];
    const float* A_im   = (const float*)d_in[3];
    const float* C_re   = (const float*)d_in[4];
    const float* C_im   = (const float*)d_in[5];
    const float* Dv     = (const float*)d_in[6];
    const float* Wout   = (const float*)d_in[7];
    const float* bout   = (const float*)d_in[8];
    const float* lng    = (const float*)d_in[9];
    const float* lnb    = (const float*)d_in[10];
    float* out = (float*)d_out;

    float* u    = (float*)d_ws;                         // B*H*L floats (33.5 MB)
    float* Wt   = u + (size_t)B * H * L;                // NL*H*O2
    float4* prm = (float4*)(Wt + (size_t)NL * H * O2);  // NL*H*N2 float4
    float2* prmT = (float2*)(prm + (size_t)NL * H * N2);// NL*H*N2 float2
    float2* send = (float2*)(prmT + (size_t)NL * H * N2); // B*H*CCH*N2 float2 (4.2 MB)
    float* y = out;                                     // reuse d_out as y scratch

    k_prm<<<(NL * H * N2 + 255) / 256, 256, 0, stream>>>(log_dt, log_Ar, A_im, C_re, C_im, prm, prmT);
    k_tr_w<<<dim3(16, 8, NL), 256, 0, stream>>>(Wout, Wt);
    k_tr_xu<<<dim3(8, 128, B), 256, 0, stream>>>(x, u);
    for (int layer = 0; layer < NL; ++layer) {
        k_scanA<<<B * H * CCH / 2, 64, 0, stream>>>(u, prm + (size_t)layer * H * N2, send);
        k_scanC<<<B * H * CCH / 2, 64, 0, stream>>>(u, prm + (size_t)layer * H * N2,
                                                    prmT + (size_t)layer * H * N2,
                                                    Dv + layer * H, send, y);
        k_gemm<<<B * L / TL, 256, 0, stream>>>(y, u, Wt + (size_t)layer * H * O2,
                                               bout + layer * O2, lng + layer * H, lnb + layer * H);
    }
    k_tr_uo<<<dim3(8, 128, B), 256, 0, stream>>>(u, out);
}

// Round 3
// 709.218 us; speedup vs baseline: 2.9965x; 1.6051x over previous
//
#include <hip/hip_runtime.h>
#include <math.h>

#define B   8
#define L   4096
#define H   256
#define N2  32
#define NL  4
#define O2  512   // 2H
#define TL  32    // gemm l-tile
#define CCH 8     // scan chunks per row
#define TCH 512   // scan chunk length (L/CCH)
#define YPAD 264  // yS row stride in bf16 elems (16B-aligned, conflict-friendly)

typedef __attribute__((ext_vector_type(8))) short short8;
typedef __attribute__((ext_vector_type(4))) float f32x4;

__device__ __forceinline__ unsigned short f2bf(float f)
{
    unsigned int u = __float_as_uint(f);
    unsigned int r = (u + 0x7fffu + ((u >> 16) & 1u)) >> 16;
    return (unsigned short)r;
}

// ---------------- precompute per-(layer,h,n): w = exp(dt*A), cm2 = 2*C*(w-1)/A, wT = w^TCH ----------------
__global__ __launch_bounds__(256) void k_prm(
    const float* __restrict__ log_dt, const float* __restrict__ log_Ar,
    const float* __restrict__ A_im, const float* __restrict__ C_re,
    const float* __restrict__ C_im, float4* __restrict__ prm,
    float2* __restrict__ prmT)
{
    int idx = blockIdx.x * 256 + threadIdx.x;     // NL*H*N2 = 32768
    if (idx >= NL * H * N2) return;
    int layer = idx / (H * N2);
    int rem = idx - layer * (H * N2);
    int h = rem / N2;
    double dt = exp((double)log_dt[layer * H + h]);
    double Ar = -exp((double)log_Ar[idx]);
    double Ai = (double)A_im[idx];
    double dtr = dt * Ar, dti = dt * Ai;
    double er = exp(dtr);
    double wr = er * cos(dti), wi = er * sin(dti);
    double numr = wr - 1.0, numi = wi;
    double den = Ar * Ar + Ai * Ai;
    double qr = (numr * Ar + numi * Ai) / den;
    double qi = (numi * Ar - numr * Ai) / den;
    double cr = (double)C_re[idx], ci = (double)C_im[idx];
    double cmr = cr * qr - ci * qi;
    double cmi = cr * qi + ci * qr;
    prm[idx] = make_float4((float)wr, (float)wi, (float)(2.0 * cmr), (float)(2.0 * cmi));
    double eT = exp(dtr * (double)TCH);
    double aT = dti * (double)TCH;
    prmT[idx] = make_float2((float)(eT * cos(aT)), (float)(eT * sin(aT)));
}

// ---------------- Wout fp32 -> bf16 (same (o,h) layout) ----------------
__global__ __launch_bounds__(256) void k_wcvt(const float* __restrict__ w, unsigned short* __restrict__ wb)
{
    int idx = (blockIdx.x * 256 + threadIdx.x) * 4;   // NL*O2*H = 524288
    float4 v = *(const float4*)(w + idx);
    ushort4 o;
    o.x = f2bf(v.x); o.y = f2bf(v.y); o.z = f2bf(v.z); o.w = f2bf(v.w);
    *(ushort4*)(wb + idx) = o;
}

// ---------------- transposes (32x32 LDS tiles) ----------------
__global__ __launch_bounds__(256) void k_tr_xu(const float* __restrict__ x, float* __restrict__ u)
{
    __shared__ float t[32][33];
    int b = blockIdx.z;
    int h0 = blockIdx.x * 32, l0 = blockIdx.y * 32;
    int tx = threadIdx.x & 31, ty = threadIdx.x >> 5;   // ty 0..7
    const float* xb = x + (size_t)b * L * H;
    float* ub = u + (size_t)b * H * L;
#pragma unroll
    for (int i = 0; i < 4; ++i)
        t[ty + i * 8][tx] = xb[(size_t)(l0 + ty + i * 8) * H + h0 + tx];
    __syncthreads();
#pragma unroll
    for (int i = 0; i < 4; ++i)
        ub[(size_t)(h0 + ty + i * 8) * L + l0 + tx] = t[tx][ty + i * 8];
}

__global__ __launch_bounds__(256) void k_tr_uo(const float* __restrict__ u, float* __restrict__ o)
{
    __shared__ float t[32][33];
    int b = blockIdx.z;
    int h0 = blockIdx.x * 32, l0 = blockIdx.y * 32;
    int tx = threadIdx.x & 31, ty = threadIdx.x >> 5;
    const float* ub = u + (size_t)b * H * L;
    float* ob = o + (size_t)b * L * H;
#pragma unroll
    for (int i = 0; i < 4; ++i)
        t[ty + i * 8][tx] = ub[(size_t)(h0 + ty + i * 8) * L + l0 + tx];
    __syncthreads();
#pragma unroll
    for (int i = 0; i < 4; ++i)
        ob[(size_t)(l0 + ty + i * 8) * H + h0 + tx] = t[tx][ty + i * 8];
}

__device__ __forceinline__ float gelu_f(float x)
{
    return 0.5f * x * (1.0f + erff(x * 0.70710678118654752f));
}

// ---------------- scan pass A: per-chunk end states (zero init) ----------------
__global__ __launch_bounds__(64) void k_scanA(
    const float* __restrict__ u, const float4* __restrict__ prm,
    float2* __restrict__ send)
{
    __shared__ float uS[2][64];
    const int t = threadIdx.x;
    const int g = t >> 5, n = t & 31;
    const int id = blockIdx.x * 2 + g;
    const int c = id & (CCH - 1);
    const int bh = id >> 3;               // log2(CCH)=3
    const int h = bh & (H - 1);
    const float4 p = prm[h * N2 + n];
    const float wr = p.x, wi = p.y;
    const float* __restrict__ urow = u + (size_t)bh * L + c * TCH;
    float sr = 0.f, si = 0.f;
    for (int l0 = 0; l0 < TCH; l0 += 64) {
        __syncthreads();
        float2 uv2 = *(const float2*)(urow + l0 + 2 * n);
        uS[g][2 * n]     = uv2.x;
        uS[g][2 * n + 1] = uv2.y;
        __syncthreads();
#pragma unroll
        for (int j = 0; j < 64; ++j) {
            float uv = uS[g][j];
            float nsr = fmaf(wr, sr, fmaf(-wi, si, uv));
            float nsi = fmaf(wr, si, wi * sr);
            sr = nsr; si = nsi;
        }
    }
    send[((size_t)bh * CCH + c) * N2 + n] = make_float2(sr, si);
}

// ---------------- scan pass C: full scan with init states + fused D-skip + GELU ----------------
__global__ __launch_bounds__(64) void k_scanC(
    const float* __restrict__ u, const float4* __restrict__ prm,
    const float2* __restrict__ prmT, const float* __restrict__ Dv,
    const float2* __restrict__ send, float* __restrict__ y)
{
    __shared__ float uS[2][32];
    __shared__ float tile[2][32 * 33];
    const int t = threadIdx.x;
    const int g = t >> 5, n = t & 31;
    const int id = blockIdx.x * 2 + g;
    const int c = id & (CCH - 1);
    const int bh = id >> 3;
    const int h = bh & (H - 1);
    const float4 p = prm[h * N2 + n];
    const float wr = p.x, wi = p.y, cr = p.z, ci = p.w;
    const float Dh = Dv[h];
    const float2 wT = prmT[h * N2 + n];
    const float* __restrict__ urow = u + (size_t)bh * L + c * TCH;
    float* __restrict__ yrow = y + (size_t)bh * L + c * TCH;

    float sr = 0.f, si = 0.f;
    for (int cp = 0; cp < c; ++cp) {
        float2 se = send[((size_t)bh * CCH + cp) * N2 + n];
        float nr = fmaf(wT.x, sr, fmaf(-wT.y, si, se.x));
        float ni = fmaf(wT.x, si, fmaf(wT.y, sr, se.y));
        sr = nr; si = ni;
    }

    float* __restrict__ tg = tile[g];
    for (int l0 = 0; l0 < TCH; l0 += 32) {
        __syncthreads();
        uS[g][n] = urow[l0 + n];
        __syncthreads();
#pragma unroll
        for (int j = 0; j < 32; ++j) {
            float uv = uS[g][j];
            float nsr = fmaf(wr, sr, fmaf(-wi, si, uv));
            float nsi = fmaf(wr, si, wi * sr);
            sr = nsr; si = nsi;
            tg[j * 33 + n] = fmaf(cr, sr, -(ci * si));
        }
        __syncthreads();
        float acc = 0.f;
#pragma unroll
        for (int k = 0; k < 32; ++k) acc += tg[n * 33 + k];
        yrow[l0 + n] = gelu_f(fmaf(Dh, uS[g][n], acc));
    }
}

// ---------------- MFMA GEMM(512x256 @ 256x32) + bias + GLU + residual + channel-LN (in-place u) ----------------
// Per block: batch b, 32-l tile. Wave wv covers o in [wv*64, wv*64+64) (p=0, "a")
// and [256+wv*64, 256+wv*64+64) (p=1, "gate") -> GLU pairs are in-register.
__global__ __launch_bounds__(256) void k_gemm(
    const float* __restrict__ y, float* __restrict__ u,
    const unsigned short* __restrict__ Wb, const float* __restrict__ bo,
    const float* __restrict__ lng, const float* __restrict__ lnb)
{
    __shared__ __align__(16) unsigned short yS[32 * YPAD];  // [l][h] bf16, 16.9 KB
    __shared__ float bS[O2];
    __shared__ float lgS[H], lbS[H];
    __shared__ float redS[4][2][16], redQ[4][2][16];

    const int t = threadIdx.x;
    const int wv = t >> 6;
    const int lane = t & 63;
    const int lanei = lane & 15;
    const int quad = lane >> 4;
    const int bid = blockIdx.x;
    const int b = bid >> 7;                 // L/TL = 128 tiles per batch
    const int l0 = (bid & 127) * TL;

    // ---- stage y tile (256h x 32l fp32) -> yS[l][h] bf16 ----
    {
        const int i = t & 7, hr = t >> 3;
        const float* yb = y + (size_t)b * H * L + l0 + i * 4;
#pragma unroll
        for (int ps = 0; ps < 8; ++ps) {
            int h = ps * 32 + hr;
            float4 v = *(const float4*)(yb + (size_t)h * L);
            yS[(i * 4 + 0) * YPAD + h] = f2bf(v.x);
            yS[(i * 4 + 1) * YPAD + h] = f2bf(v.y);
            yS[(i * 4 + 2) * YPAD + h] = f2bf(v.z);
            yS[(i * 4 + 3) * YPAD + h] = f2bf(v.w);
        }
        for (int idx = t; idx < O2; idx += 256) bS[idx] = bo[idx];
        lgS[t & 255] = lng[t & 255];
        lbS[t & 255] = lnb[t & 255];
    }
    __syncthreads();

    // ---- MFMA main loop: D[o][l] = sum_h Wb[o][h] * yS[l][h] ----
    f32x4 acc[2][4][2];
#pragma unroll
    for (int p = 0; p < 2; ++p)
#pragma unroll
        for (int j = 0; j < 4; ++j)
#pragma unroll
            for (int nt = 0; nt < 2; ++nt)
                acc[p][j][nt] = (f32x4){0.f, 0.f, 0.f, 0.f};

    // per-lane A row base offsets (elements)
    size_t abase[2][4];
#pragma unroll
    for (int p = 0; p < 2; ++p)
#pragma unroll
        for (int j = 0; j < 4; ++j) {
            int o = p * 256 + wv * 64 + j * 16 + lanei;
            abase[p][j] = (size_t)o * H + quad * 8;
        }

#pragma unroll
    for (int kt = 0; kt < 8; ++kt) {
        short8 bfr[2];
#pragma unroll
        for (int nt = 0; nt < 2; ++nt)
            bfr[nt] = *(const short8*)&yS[(nt * 16 + lanei) * YPAD + kt * 32 + quad * 8];
#pragma unroll
        for (int p = 0; p < 2; ++p)
#pragma unroll
            for (int j = 0; j < 4; ++j) {
                short8 a8 = *(const short8*)(Wb + abase[p][j] + kt * 32);
#pragma unroll
                for (int nt = 0; nt < 2; ++nt)
                    acc[p][j][nt] = __builtin_amdgcn_mfma_f32_16x16x32_bf16(
                        a8, bfr[nt], acc[p][j][nt], 0, 0, 0);
            }
    }

    // ---- epilogue: bias + GLU + residual; accumulate LN stats ----
    float psum[2] = {0.f, 0.f}, psq[2] = {0.f, 0.f};
    float* ub = u + (size_t)b * H * L + l0;
#pragma unroll
    for (int j = 0; j < 4; ++j) {
        int orow = wv * 64 + j * 16 + quad * 4;   // h rows orow..orow+3
#pragma unroll
        for (int nt = 0; nt < 2; ++nt) {
            int lc = nt * 16 + lanei;
#pragma unroll
            for (int reg = 0; reg < 4; ++reg) {
                int o = orow + reg;
                float a = acc[0][j][nt][reg] + bS[o];
                float g = acc[1][j][nt][reg] + bS[o + 256];
                float glu = a / (1.f + expf(-g));
                float res = ub[(size_t)o * L + lc];
                float val = glu + res;
                acc[0][j][nt][reg] = val;
                psum[nt] += val;
                psq[nt] = fmaf(val, val, psq[nt]);
            }
        }
    }
    // quad reduction (lanes with same lanei across quads)
#pragma unroll
    for (int nt = 0; nt < 2; ++nt) {
        psum[nt] += __shfl_xor(psum[nt], 16);
        psum[nt] += __shfl_xor(psum[nt], 32);
        psq[nt]  += __shfl_xor(psq[nt], 16);
        psq[nt]  += __shfl_xor(psq[nt], 32);
    }
    if (lane < 16) {
#pragma unroll
        for (int nt = 0; nt < 2; ++nt) {
            redS[wv][nt][lanei] = psum[nt];
            redQ[wv][nt][lanei] = psq[nt];
        }
    }
    __syncthreads();
    float mcol[2], icol[2];
#pragma unroll
    for (int nt = 0; nt < 2; ++nt) {
        float s = redS[0][nt][lanei] + redS[1][nt][lanei] + redS[2][nt][lanei] + redS[3][nt][lanei];
        float q = redQ[0][nt][lanei] + redQ[1][nt][lanei] + redQ[2][nt][lanei] + redQ[3][nt][lanei];
        float m = s * (1.0f / 256.0f);
        float v = q * (1.0f / 256.0f) - m * m;
        mcol[nt] = m;
        icol[nt] = rsqrtf(v + 1e-5f);
    }
    // ---- LN scale/shift + store (in-place u) ----
#pragma unroll
    for (int j = 0; j < 4; ++j) {
        int orow = wv * 64 + j * 16 + quad * 4;
#pragma unroll
        for (int nt = 0; nt < 2; ++nt) {
            int lc = nt * 16 + lanei;
#pragma unroll
            for (int reg = 0; reg < 4; ++reg) {
                int o = orow + reg;
                float val = acc[0][j][nt][reg];
                float ov = (val - mcol[nt]) * icol[nt] * lgS[o] + lbS[o];
                ub[(size_t)o * L + lc] = ov;
            }
        }
    }
}

extern "C" void kernel_launch(void* const* d_in, const int* in_sizes, int n_in,
                              void* d_out, int out_size, void* d_ws, size_t ws_size,
                              hipStream_t stream)
{
    const float* x      = (const float*)d_in[0];
    const float* log_dt = (const float*)d_in[1];
    const float* log_Ar = (const float*)d_in[2];
    const float* A_im   = (const float*)d_in[3];
    const float* C_re   = (const float*)d_in[4];
    const float* C_im   = (const float*)d_in[5];
    const float* Dv     = (const float*)d_in[6];
    const float* Wout   = (const float*)d_in[7];
    const float* bout   = (const float*)d_in[8];
    const float* lng    = (const float*)d_in[9];
    const float* lnb    = (const float*)d_in[10];
    float* out = (float*)d_out;

    float* u    = (float*)d_ws;                          // B*H*L floats (33.5 MB)
    unsigned short* Wb = (unsigned short*)(u + (size_t)B * H * L);  // NL*O2*H bf16 (1 MB)
    float4* prm  = (float4*)(Wb + (size_t)NL * O2 * H);  // NL*H*N2 float4
    float2* prmT = (float2*)(prm + (size_t)NL * H * N2); // NL*H*N2 float2
    float2* send = prmT + (size_t)NL * H * N2;           // B*H*CCH*N2 float2 (4.2 MB)
    float* y = out;                                      // reuse d_out as y scratch

    k_prm<<<(NL * H * N2 + 255) / 256, 256, 0, stream>>>(log_dt, log_Ar, A_im, C_re, C_im, prm, prmT);
    k_wcvt<<<NL * O2 * H / 1024, 256, 0, stream>>>(Wout, Wb);
    k_tr_xu<<<dim3(8, 128, B), 256, 0, stream>>>(x, u);
    for (int layer = 0; layer < NL; ++layer) {
        k_scanA<<<B * H * CCH / 2, 64, 0, stream>>>(u, prm + (size_t)layer * H * N2, send);
        k_scanC<<<B * H * CCH / 2, 64, 0, stream>>>(u, prm + (size_t)layer * H * N2,
                                                    prmT + (size_t)layer * H * N2,
                                                    Dv + layer * H, send, y);
        k_gemm<<<B * L / TL, 256, 0, stream>>>(y, u, Wb + (size_t)layer * O2 * H,
                                               bout + layer * O2, lng + layer * H, lnb + layer * H);
    }
    k_tr_uo<<<dim3(8, 128, B), 256, 0, stream>>>(u, out);
}

// Round 4
// 524.851 us; speedup vs baseline: 4.0491x; 1.3513x over previous
//
#include <hip/hip_runtime.h>
#include <math.h>

#define B    8
#define L    4096
#define H    256
#define N2   32
#define NL   4
#define O2   512   // 2H
#define TL   32    // gemm l-tile
#define BLK  64    // scan block length
#define NBLK 64    // L/BLK
#define TVP  136   // TVc row stride (elems): 64 T + 64 Vc + 8 pad (272B, 16B-mult)
#define MJP  72    // Mm row stride (144B, 16B-mult)
#define UTP  72    // uT/ST LDS row stride (144B, 16B-mult, 2-way banks)
#define YPAD 264   // k_gemm yS row stride

typedef __attribute__((ext_vector_type(8))) short short8;
typedef __attribute__((ext_vector_type(4))) float f32x4;

__device__ __forceinline__ unsigned short f2bf(float f)
{
    unsigned int u = __float_as_uint(f);
    unsigned int r = (u + 0x7fffu + ((u >> 16) & 1u)) >> 16;
    return (unsigned short)r;
}

__device__ __forceinline__ float gelu_f(float x)
{
    return 0.5f * x * (1.0f + erff(x * 0.70710678118654752f));
}

// ---------------- per-(layer,h,n) params: w = exp(dt*A), cm2 = 2*C*(w-1)/A ----------------
__global__ __launch_bounds__(256) void k_prm(
    const float* __restrict__ log_dt, const float* __restrict__ log_Ar,
    const float* __restrict__ A_im, const float* __restrict__ C_re,
    const float* __restrict__ C_im, float4* __restrict__ prm)
{
    int idx = blockIdx.x * 256 + threadIdx.x;     // NL*H*N2 = 32768
    if (idx >= NL * H * N2) return;
    int layer = idx / (H * N2);
    int rem = idx - layer * (H * N2);
    int h = rem / N2;
    double dt = exp((double)log_dt[layer * H + h]);
    double Ar = -exp((double)log_Ar[idx]);
    double Ai = (double)A_im[idx];
    double dtr = dt * Ar, dti = dt * Ai;
    double er = exp(dtr);
    double wr = er * cos(dti), wi = er * sin(dti);
    double numr = wr - 1.0, numi = wi;
    double den = Ar * Ar + Ai * Ai;
    double qr = (numr * Ar + numi * Ai) / den;
    double qi = (numi * Ar - numr * Ai) / den;
    double cr = (double)C_re[idx], ci = (double)C_im[idx];
    double cmr = cr * qr - ci * qi;
    double cmi = cr * qi + ci * qr;
    prm[idx] = make_float4((float)wr, (float)wi, (float)(2.0 * cmr), (float)(2.0 * cmi));
}

// ---------------- build per-(layer,h) matrices: T|Vc (64x136), M (64x72), w^64 ----------------
__global__ __launch_bounds__(64) void k_mats(
    const float4* __restrict__ prm, const float* __restrict__ Dv,
    unsigned short* __restrict__ TVc, unsigned short* __restrict__ Mm,
    float2* __restrict__ w64c)
{
    __shared__ float kb[2][BLK];
    const int t = threadIdx.x;
    const int g = t >> 5, n = t & 31;
    const int id = blockIdx.x * 2 + g;       // NL*H ids
    const int layer = id >> 8, h = id & 255;
    const float4 p = prm[(layer * H + h) * N2 + n];
    const float wr = p.x, wi = p.y, cr = p.z, ci = p.w;
    const float Dh = Dv[layer * H + h];
    unsigned short* tv = TVc + (size_t)(layer * H + h) * BLK * TVP;
    unsigned short* mm = Mm + (size_t)(layer * H + h) * BLK * MJP;
    float vr = 1.f, vi = 0.f;                // w^0
    for (int d = 0; d < BLK; ++d) {
        // k[d] = sum_n Re(cm2 * w^d)
        float pk = fmaf(cr, vr, -(ci * vi));
        pk += __shfl_xor(pk, 1);  pk += __shfl_xor(pk, 2);
        pk += __shfl_xor(pk, 4);  pk += __shfl_xor(pk, 8);
        pk += __shfl_xor(pk, 16);
        if (n == 0) kb[g][d] = pk;
        // M[k=n][j=63-d] = Re(w^d); M[32+n][63-d] = Im(w^d)
        mm[n * MJP + (63 - d)]        = f2bf(vr);
        mm[(32 + n) * MJP + (63 - d)] = f2bf(vi);
        // v *= w  -> w^{d+1}
        float nvr = vr * wr - vi * wi;
        float nvi = vr * wi + vi * wr;
        vr = nvr; vi = nvi;
        // Vc[i=d][n] = Re(cm2 w^{d+1}); [32+n] = -Im(cm2 w^{d+1})
        float qr = fmaf(cr, vr, -(ci * vi));
        float qi = fmaf(cr, vi, ci * vr);
        tv[d * TVP + 64 + n] = f2bf(qr);
        tv[d * TVP + 96 + n] = f2bf(-qi);
    }
    w64c[(layer * H + h) * N2 + n] = make_float2(vr, vi);
    __syncthreads();
    // T[i][j] = k[i-j] (j<i), k[0]+Dh (j==i), 0 (j>i)
    for (int i = 0; i < BLK; ++i) {
#pragma unroll
        for (int hf = 0; hf < 2; ++hf) {
            int j = n + hf * 32;
            float val = (j > i) ? 0.f : ((j == i) ? (kb[g][0] + Dh) : kb[g][i - j]);
            tv[i * TVP + j] = f2bf(val);
        }
    }
}

// ---------------- transposes (32x32 LDS tiles) ----------------
__global__ __launch_bounds__(256) void k_tr_xu(const float* __restrict__ x, float* __restrict__ u)
{
    __shared__ float t[32][33];
    int b = blockIdx.z;
    int h0 = blockIdx.x * 32, l0 = blockIdx.y * 32;
    int tx = threadIdx.x & 31, ty = threadIdx.x >> 5;
    const float* xb = x + (size_t)b * L * H;
    float* ub = u + (size_t)b * H * L;
#pragma unroll
    for (int i = 0; i < 4; ++i)
        t[ty + i * 8][tx] = xb[(size_t)(l0 + ty + i * 8) * H + h0 + tx];
    __syncthreads();
#pragma unroll
    for (int i = 0; i < 4; ++i)
        ub[(size_t)(h0 + ty + i * 8) * L + l0 + tx] = t[tx][ty + i * 8];
}

__global__ __launch_bounds__(256) void k_tr_uo(const float* __restrict__ u, float* __restrict__ o)
{
    __shared__ float t[32][33];
    int b = blockIdx.z;
    int h0 = blockIdx.x * 32, l0 = blockIdx.y * 32;
    int tx = threadIdx.x & 31, ty = threadIdx.x >> 5;
    const float* ub = u + (size_t)b * H * L;
    float* ob = o + (size_t)b * L * H;
#pragma unroll
    for (int i = 0; i < 4; ++i)
        t[ty + i * 8][tx] = ub[(size_t)(h0 + ty + i * 8) * L + l0 + tx];
    __syncthreads();
#pragma unroll
    for (int i = 0; i < 4; ++i)
        ob[(size_t)(l0 + ty + i * 8) * H + h0 + tx] = t[tx][ty + i * 8];
}

// ---------------- Wout fp32 -> bf16 ----------------
__global__ __launch_bounds__(256) void k_wcvt(const float* __restrict__ w, unsigned short* __restrict__ wb)
{
    int idx = (blockIdx.x * 256 + threadIdx.x) * 4;   // NL*O2*H = 524288
    float4 v = *(const float4*)(w + idx);
    ushort4 o;
    o.x = f2bf(v.x); o.y = f2bf(v.y); o.z = f2bf(v.z); o.w = f2bf(v.w);
    *(ushort4*)(wb + idx) = o;
}

// ---------------- GEMM-A: INC[b,h,blk][k] = sum_j M[h][k][j] * u[b,h,blk*64+j] ----------------
__global__ __launch_bounds__(256) void k_ga(
    const float* __restrict__ u, const unsigned short* __restrict__ Mm_l,
    float* __restrict__ INC)
{
    __shared__ __align__(16) unsigned short uT[BLK * UTP];
    const int t = threadIdx.x;
    const int wv = t >> 6, lane = t & 63;
    const int lanei = lane & 15, quad = lane >> 4;
    const int h = blockIdx.x >> 3, ct = blockIdx.x & 7;
    const float* ub = u + (size_t)(ct * H + h) * L;
    {   // stage uT[col=blk][j] bf16
        int col = t >> 2, q = t & 3;
#pragma unroll
        for (int i = 0; i < 4; ++i) {
            float4 v = *(const float4*)(ub + col * 64 + q * 16 + i * 4);
            ushort4 o4;
            o4.x = f2bf(v.x); o4.y = f2bf(v.y); o4.z = f2bf(v.z); o4.w = f2bf(v.w);
            *(ushort4*)&uT[col * UTP + q * 16 + i * 4] = o4;
        }
    }
    __syncthreads();
    f32x4 acc[4];
#pragma unroll
    for (int nt = 0; nt < 4; ++nt) acc[nt] = (f32x4){0.f, 0.f, 0.f, 0.f};
    const unsigned short* arow = Mm_l + (size_t)h * BLK * MJP + (wv * 16 + lanei) * MJP + quad * 8;
#pragma unroll
    for (int kt = 0; kt < 2; ++kt) {
        short8 a8 = *(const short8*)(arow + kt * 32);
#pragma unroll
        for (int nt = 0; nt < 4; ++nt) {
            short8 b8 = *(const short8*)&uT[(nt * 16 + lanei) * UTP + kt * 32 + quad * 8];
            acc[nt] = __builtin_amdgcn_mfma_f32_16x16x32_bf16(a8, b8, acc[nt], 0, 0, 0);
        }
    }
    float* ibase = INC + (size_t)(ct * H + h) * NBLK * 64;
#pragma unroll
    for (int nt = 0; nt < 4; ++nt) {
        int col = nt * 16 + lanei;
        int k0 = wv * 16 + quad * 4;
        *(f32x4*)(ibase + (size_t)col * 64 + k0) = acc[nt];
    }
}

// ---------------- chain: serial over 64 blocks per (b,h); store prefix states bf16 ----------------
__global__ __launch_bounds__(64) void k_chain(
    const float* __restrict__ INC, const float2* __restrict__ w64c_l,
    unsigned short* __restrict__ Sb)
{
    const int t = threadIdx.x, g = t >> 5, n = t & 31;
    const int unit = blockIdx.x * 2 + g;   // b*H + h
    const int h = unit & 255;
    const float2 w64 = w64c_l[h * N2 + n];
    const float* ib = INC + (size_t)unit * NBLK * 64;
    unsigned short* sb = Sb + (size_t)unit * NBLK * 64;
    float sr = 0.f, si = 0.f;
    for (int blk = 0; blk < NBLK; ++blk) {
        sb[blk * 64 + n]      = f2bf(sr);
        sb[blk * 64 + 32 + n] = f2bf(si);
        float ir = ib[blk * 64 + n];
        float ii = ib[blk * 64 + 32 + n];
        float nr = fmaf(w64.x, sr, fmaf(-w64.y, si, ir));
        float ni = fmaf(w64.x, si, fmaf(w64.y, sr, ii));
        sr = nr; si = ni;
    }
}

// ---------------- GEMM-B: y = gelu(T*U + Vc*S) (D folded into T diag) ----------------
__global__ __launch_bounds__(256) void k_gb(
    const float* __restrict__ u, const unsigned short* __restrict__ Sb,
    const unsigned short* __restrict__ TVc_l, float* __restrict__ y)
{
    __shared__ __align__(16) unsigned short uT[BLK * UTP];
    __shared__ __align__(16) unsigned short ST[BLK * UTP];
    const int t = threadIdx.x;
    const int wv = t >> 6, lane = t & 63;
    const int lanei = lane & 15, quad = lane >> 4;
    const int h = blockIdx.x >> 3, ct = blockIdx.x & 7;
    const float* ub = u + (size_t)(ct * H + h) * L;
    const unsigned short* sbg = Sb + (size_t)(ct * H + h) * NBLK * 64;
    {
        int col = t >> 2, q = t & 3;
#pragma unroll
        for (int i = 0; i < 4; ++i) {
            float4 v = *(const float4*)(ub + col * 64 + q * 16 + i * 4);
            ushort4 o4;
            o4.x = f2bf(v.x); o4.y = f2bf(v.y); o4.z = f2bf(v.z); o4.w = f2bf(v.w);
            *(ushort4*)&uT[col * UTP + q * 16 + i * 4] = o4;
        }
#pragma unroll
        for (int i = 0; i < 2; ++i)
            *(short8*)&ST[col * UTP + q * 16 + i * 8] =
                *(const short8*)(sbg + col * 64 + q * 16 + i * 8);
    }
    __syncthreads();
    f32x4 acc[4];
#pragma unroll
    for (int nt = 0; nt < 4; ++nt) acc[nt] = (f32x4){0.f, 0.f, 0.f, 0.f};
    const unsigned short* arow = TVc_l + (size_t)h * BLK * TVP + (wv * 16 + lanei) * TVP + quad * 8;
#pragma unroll
    for (int kt = 0; kt < 4; ++kt) {
        short8 a8 = *(const short8*)(arow + kt * 32);
        const unsigned short* bb = (kt < 2) ? uT : ST;
        int ko = (kt & 1) * 32 + quad * 8;
#pragma unroll
        for (int nt = 0; nt < 4; ++nt) {
            short8 b8 = *(const short8*)&bb[(nt * 16 + lanei) * UTP + ko];
            acc[nt] = __builtin_amdgcn_mfma_f32_16x16x32_bf16(a8, b8, acc[nt], 0, 0, 0);
        }
    }
    float* yb = y + (size_t)(ct * H + h) * L;
#pragma unroll
    for (int nt = 0; nt < 4; ++nt) {
        int blk = nt * 16 + lanei;
        int i0 = wv * 16 + quad * 4;
        float4 ov;
        ov.x = gelu_f(acc[nt][0]);
        ov.y = gelu_f(acc[nt][1]);
        ov.z = gelu_f(acc[nt][2]);
        ov.w = gelu_f(acc[nt][3]);
        *(float4*)(yb + (size_t)blk * 64 + i0) = ov;
    }
}

// ---------------- MFMA GEMM(512x256 @ 256x32) + bias + GLU + residual + channel-LN ----------------
__global__ __launch_bounds__(256) void k_gemm(
    const float* __restrict__ y, float* __restrict__ u,
    const unsigned short* __restrict__ Wb, const float* __restrict__ bo,
    const float* __restrict__ lng, const float* __restrict__ lnb)
{
    __shared__ __align__(16) unsigned short yS[32 * YPAD];
    __shared__ float bS[O2];
    __shared__ float lgS[H], lbS[H];
    __shared__ float redS[4][2][16], redQ[4][2][16];

    const int t = threadIdx.x;
    const int wv = t >> 6;
    const int lane = t & 63;
    const int lanei = lane & 15;
    const int quad = lane >> 4;
    const int bid = blockIdx.x;
    const int b = bid >> 7;
    const int l0 = (bid & 127) * TL;

    {
        const int i = t & 7, hr = t >> 3;
        const float* yb = y + (size_t)b * H * L + l0 + i * 4;
#pragma unroll
        for (int ps = 0; ps < 8; ++ps) {
            int h = ps * 32 + hr;
            float4 v = *(const float4*)(yb + (size_t)h * L);
            yS[(i * 4 + 0) * YPAD + h] = f2bf(v.x);
            yS[(i * 4 + 1) * YPAD + h] = f2bf(v.y);
            yS[(i * 4 + 2) * YPAD + h] = f2bf(v.z);
            yS[(i * 4 + 3) * YPAD + h] = f2bf(v.w);
        }
        for (int idx = t; idx < O2; idx += 256) bS[idx] = bo[idx];
        lgS[t & 255] = lng[t & 255];
        lbS[t & 255] = lnb[t & 255];
    }
    __syncthreads();

    f32x4 acc[2][4][2];
#pragma unroll
    for (int p = 0; p < 2; ++p)
#pragma unroll
        for (int j = 0; j < 4; ++j)
#pragma unroll
            for (int nt = 0; nt < 2; ++nt)
                acc[p][j][nt] = (f32x4){0.f, 0.f, 0.f, 0.f};

    size_t abase[2][4];
#pragma unroll
    for (int p = 0; p < 2; ++p)
#pragma unroll
        for (int j = 0; j < 4; ++j) {
            int o = p * 256 + wv * 64 + j * 16 + lanei;
            abase[p][j] = (size_t)o * H + quad * 8;
        }

    // software-pipelined A (W) loads
    short8 a8c[8];
#pragma unroll
    for (int p = 0; p < 2; ++p)
#pragma unroll
        for (int j = 0; j < 4; ++j)
            a8c[p * 4 + j] = *(const short8*)(Wb + abase[p][j]);

#pragma unroll
    for (int kt = 0; kt < 8; ++kt) {
        short8 bfr[2];
#pragma unroll
        for (int nt = 0; nt < 2; ++nt)
            bfr[nt] = *(const short8*)&yS[(nt * 16 + lanei) * YPAD + kt * 32 + quad * 8];
        short8 a8n[8];
        if (kt < 7) {
#pragma unroll
            for (int p = 0; p < 2; ++p)
#pragma unroll
                for (int j = 0; j < 4; ++j)
                    a8n[p * 4 + j] = *(const short8*)(Wb + abase[p][j] + (kt + 1) * 32);
        }
#pragma unroll
        for (int p = 0; p < 2; ++p)
#pragma unroll
            for (int j = 0; j < 4; ++j)
#pragma unroll
                for (int nt = 0; nt < 2; ++nt)
                    acc[p][j][nt] = __builtin_amdgcn_mfma_f32_16x16x32_bf16(
                        a8c[p * 4 + j], bfr[nt], acc[p][j][nt], 0, 0, 0);
        if (kt < 7) {
#pragma unroll
            for (int q = 0; q < 8; ++q) a8c[q] = a8n[q];
        }
    }

    float psum[2] = {0.f, 0.f}, psq[2] = {0.f, 0.f};
    float* ub = u + (size_t)b * H * L + l0;
#pragma unroll
    for (int j = 0; j < 4; ++j) {
        int orow = wv * 64 + j * 16 + quad * 4;
#pragma unroll
        for (int nt = 0; nt < 2; ++nt) {
            int lc = nt * 16 + lanei;
#pragma unroll
            for (int reg = 0; reg < 4; ++reg) {
                int o = orow + reg;
                float a = acc[0][j][nt][reg] + bS[o];
                float g = acc[1][j][nt][reg] + bS[o + 256];
                float glu = a / (1.f + expf(-g));
                float res = ub[(size_t)o * L + lc];
                float val = glu + res;
                acc[0][j][nt][reg] = val;
                psum[nt] += val;
                psq[nt] = fmaf(val, val, psq[nt]);
            }
        }
    }
#pragma unroll
    for (int nt = 0; nt < 2; ++nt) {
        psum[nt] += __shfl_xor(psum[nt], 16);
        psum[nt] += __shfl_xor(psum[nt], 32);
        psq[nt]  += __shfl_xor(psq[nt], 16);
        psq[nt]  += __shfl_xor(psq[nt], 32);
    }
    if (lane < 16) {
#pragma unroll
        for (int nt = 0; nt < 2; ++nt) {
            redS[wv][nt][lanei] = psum[nt];
            redQ[wv][nt][lanei] = psq[nt];
        }
    }
    __syncthreads();
    float mcol[2], icol[2];
#pragma unroll
    for (int nt = 0; nt < 2; ++nt) {
        float s = redS[0][nt][lanei] + redS[1][nt][lanei] + redS[2][nt][lanei] + redS[3][nt][lanei];
        float q = redQ[0][nt][lanei] + redQ[1][nt][lanei] + redQ[2][nt][lanei] + redQ[3][nt][lanei];
        float m = s * (1.0f / 256.0f);
        float v = q * (1.0f / 256.0f) - m * m;
        mcol[nt] = m;
        icol[nt] = rsqrtf(v + 1e-5f);
    }
#pragma unroll
    for (int j = 0; j < 4; ++j) {
        int orow = wv * 64 + j * 16 + quad * 4;
#pragma unroll
        for (int nt = 0; nt < 2; ++nt) {
            int lc = nt * 16 + lanei;
#pragma unroll
            for (int reg = 0; reg < 4; ++reg) {
                int o = orow + reg;
                float val = acc[0][j][nt][reg];
                float ov = (val - mcol[nt]) * icol[nt] * lgS[o] + lbS[o];
                ub[(size_t)o * L + lc] = ov;
            }
        }
    }
}

extern "C" void kernel_launch(void* const* d_in, const int* in_sizes, int n_in,
                              void* d_out, int out_size, void* d_ws, size_t ws_size,
                              hipStream_t stream)
{
    const float* x      = (const float*)d_in[0];
    const float* log_dt = (const float*)d_in[1];
    const float* log_Ar = (const float*)d_in[2];
    const float* A_im   = (const float*)d_in[3];
    const float* C_re   = (const float*)d_in[4];
    const float* C_im   = (const float*)d_in[5];
    const float* Dv     = (const float*)d_in[6];
    const float* Wout   = (const float*)d_in[7];
    const float* bout   = (const float*)d_in[8];
    const float* lng    = (const float*)d_in[9];
    const float* lnb    = (const float*)d_in[10];
    float* out = (float*)d_out;

    float* u           = (float*)d_ws;                              // 33.5 MB
    unsigned short* Wb = (unsigned short*)(u + (size_t)B * H * L);  // 1 MB
    float4* prm        = (float4*)(Wb + (size_t)NL * O2 * H);       // 0.5 MB
    unsigned short* TVc = (unsigned short*)(prm + (size_t)NL * H * N2);   // 17.8 MB
    unsigned short* Mm  = TVc + (size_t)NL * H * BLK * TVP;               // 9.4 MB
    float2* w64c       = (float2*)(Mm + (size_t)NL * H * BLK * MJP);      // 0.26 MB
    unsigned short* Sb = (unsigned short*)(w64c + (size_t)NL * H * N2);   // 16.8 MB
    float* INC = out;   // aliases d_out (dead before k_gb writes y)
    float* y   = out;

    k_prm<<<(NL * H * N2 + 255) / 256, 256, 0, stream>>>(log_dt, log_Ar, A_im, C_re, C_im, prm);
    k_wcvt<<<NL * O2 * H / 1024, 256, 0, stream>>>(Wout, Wb);
    k_mats<<<NL * H / 2, 64, 0, stream>>>(prm, Dv, TVc, Mm, w64c);
    k_tr_xu<<<dim3(8, 128, B), 256, 0, stream>>>(x, u);
    for (int layer = 0; layer < NL; ++layer) {
        k_ga<<<H * 8, 256, 0, stream>>>(u, Mm + (size_t)layer * H * BLK * MJP, INC);
        k_chain<<<B * H / 2, 64, 0, stream>>>(INC, w64c + (size_t)layer * H * N2, Sb);
        k_gb<<<H * 8, 256, 0, stream>>>(u, Sb, TVc + (size_t)layer * H * BLK * TVP, y);
        k_gemm<<<B * L / TL, 256, 0, stream>>>(y, u, Wb + (size_t)layer * O2 * H,
                                               bout + layer * O2, lng + layer * H, lnb + layer * H);
    }
    k_tr_uo<<<dim3(8, 128, B), 256, 0, stream>>>(u, out);
}

// Round 5
// 472.044 us; speedup vs baseline: 4.5021x; 1.1119x over previous
//
#include <hip/hip_runtime.h>
#include <math.h>

#define B    8
#define L    4096
#define H    256
#define N2   32
#define NL   4
#define O2   512   // 2H
#define TL   32    // gemm l-tile
#define BLK  64    // scan block length
#define NBLK 64    // L/BLK
#define TVP  136   // TVc row stride (elems): 64 T + 64 Vc + 8 pad
#define MJP  72    // Mm row stride
#define UTP  72    // uT/ST LDS row stride (u16)
#define INP  66    // INC LDS row stride (f32)
#define YPAD 264   // k_gemm yS row stride (u16)

typedef __attribute__((ext_vector_type(8))) short short8;
typedef __attribute__((ext_vector_type(4))) float f32x4;

__device__ __forceinline__ unsigned short f2bf(float f)
{
    unsigned int u = __float_as_uint(f);
    unsigned int r = (u + 0x7fffu + ((u >> 16) & 1u)) >> 16;
    return (unsigned short)r;
}

__device__ __forceinline__ float gelu_f(float x)
{
    return 0.5f * x * (1.0f + erff(x * 0.70710678118654752f));
}

// ---------------- per-(layer,h,n) params: w = exp(dt*A), cm2 = 2*C*(w-1)/A ----------------
__global__ __launch_bounds__(256) void k_prm(
    const float* __restrict__ log_dt, const float* __restrict__ log_Ar,
    const float* __restrict__ A_im, const float* __restrict__ C_re,
    const float* __restrict__ C_im, float4* __restrict__ prm)
{
    int idx = blockIdx.x * 256 + threadIdx.x;     // NL*H*N2 = 32768
    if (idx >= NL * H * N2) return;
    int layer = idx / (H * N2);
    int rem = idx - layer * (H * N2);
    int h = rem / N2;
    double dt = exp((double)log_dt[layer * H + h]);
    double Ar = -exp((double)log_Ar[idx]);
    double Ai = (double)A_im[idx];
    double dtr = dt * Ar, dti = dt * Ai;
    double er = exp(dtr);
    double wr = er * cos(dti), wi = er * sin(dti);
    double numr = wr - 1.0, numi = wi;
    double den = Ar * Ar + Ai * Ai;
    double qr = (numr * Ar + numi * Ai) / den;
    double qi = (numi * Ar - numr * Ai) / den;
    double cr = (double)C_re[idx], ci = (double)C_im[idx];
    double cmr = cr * qr - ci * qi;
    double cmi = cr * qi + ci * qr;
    prm[idx] = make_float4((float)wr, (float)wi, (float)(2.0 * cmr), (float)(2.0 * cmi));
}

// ---------------- build per-(layer,h) matrices: T|Vc (64x136), M (64x72), w^64 ----------------
__global__ __launch_bounds__(64) void k_mats(
    const float4* __restrict__ prm, const float* __restrict__ Dv,
    unsigned short* __restrict__ TVc, unsigned short* __restrict__ Mm,
    float2* __restrict__ w64c)
{
    __shared__ float kb[2][BLK];
    const int t = threadIdx.x;
    const int g = t >> 5, n = t & 31;
    const int id = blockIdx.x * 2 + g;       // NL*H ids
    const int layer = id >> 8, h = id & 255;
    const float4 p = prm[(layer * H + h) * N2 + n];
    const float wr = p.x, wi = p.y, cr = p.z, ci = p.w;
    const float Dh = Dv[layer * H + h];
    unsigned short* tv = TVc + (size_t)(layer * H + h) * BLK * TVP;
    unsigned short* mm = Mm + (size_t)(layer * H + h) * BLK * MJP;
    float vr = 1.f, vi = 0.f;                // w^0
    for (int d = 0; d < BLK; ++d) {
        float pk = fmaf(cr, vr, -(ci * vi));
        pk += __shfl_xor(pk, 1);  pk += __shfl_xor(pk, 2);
        pk += __shfl_xor(pk, 4);  pk += __shfl_xor(pk, 8);
        pk += __shfl_xor(pk, 16);
        if (n == 0) kb[g][d] = pk;
        mm[n * MJP + (63 - d)]        = f2bf(vr);
        mm[(32 + n) * MJP + (63 - d)] = f2bf(vi);
        float nvr = vr * wr - vi * wi;
        float nvi = vr * wi + vi * wr;
        vr = nvr; vi = nvi;
        float qr = fmaf(cr, vr, -(ci * vi));
        float qi = fmaf(cr, vi, ci * vr);
        tv[d * TVP + 64 + n] = f2bf(qr);
        tv[d * TVP + 96 + n] = f2bf(-qi);
    }
    w64c[(layer * H + h) * N2 + n] = make_float2(vr, vi);
    __syncthreads();
    for (int i = 0; i < BLK; ++i) {
#pragma unroll
        for (int hf = 0; hf < 2; ++hf) {
            int j = n + hf * 32;
            float val = (j > i) ? 0.f : ((j == i) ? (kb[g][0] + Dh) : kb[g][i - j]);
            tv[i * TVP + j] = f2bf(val);
        }
    }
}

// ---------------- transposes (32x32 LDS tiles) ----------------
__global__ __launch_bounds__(256) void k_tr_xu(const float* __restrict__ x, float* __restrict__ u)
{
    __shared__ float t[32][33];
    int b = blockIdx.z;
    int h0 = blockIdx.x * 32, l0 = blockIdx.y * 32;
    int tx = threadIdx.x & 31, ty = threadIdx.x >> 5;
    const float* xb = x + (size_t)b * L * H;
    float* ub = u + (size_t)b * H * L;
#pragma unroll
    for (int i = 0; i < 4; ++i)
        t[ty + i * 8][tx] = xb[(size_t)(l0 + ty + i * 8) * H + h0 + tx];
    __syncthreads();
#pragma unroll
    for (int i = 0; i < 4; ++i)
        ub[(size_t)(h0 + ty + i * 8) * L + l0 + tx] = t[tx][ty + i * 8];
}

__global__ __launch_bounds__(256) void k_tr_uo(const float* __restrict__ u, float* __restrict__ o)
{
    __shared__ float t[32][33];
    int b = blockIdx.z;
    int h0 = blockIdx.x * 32, l0 = blockIdx.y * 32;
    int tx = threadIdx.x & 31, ty = threadIdx.x >> 5;
    const float* ub = u + (size_t)b * H * L;
    float* ob = o + (size_t)b * L * H;
#pragma unroll
    for (int i = 0; i < 4; ++i)
        t[ty + i * 8][tx] = ub[(size_t)(h0 + ty + i * 8) * L + l0 + tx];
    __syncthreads();
#pragma unroll
    for (int i = 0; i < 4; ++i)
        ob[(size_t)(l0 + ty + i * 8) * H + h0 + tx] = t[tx][ty + i * 8];
}

// ---------------- Wout fp32 -> bf16 ----------------
__global__ __launch_bounds__(256) void k_wcvt(const float* __restrict__ w, unsigned short* __restrict__ wb)
{
    int idx = (blockIdx.x * 256 + threadIdx.x) * 4;   // NL*O2*H = 524288
    float4 v = *(const float4*)(w + idx);
    ushort4 o;
    o.x = f2bf(v.x); o.y = f2bf(v.y); o.z = f2bf(v.z); o.w = f2bf(v.w);
    *(ushort4*)(wb + idx) = o;
}

// ---------------- fused scan: GEMM-A + chain + GEMM-B, all in LDS; y out bf16 ----------------
__global__ __launch_bounds__(256) void k_scan3(
    const float* __restrict__ u, const unsigned short* __restrict__ Mm_l,
    const unsigned short* __restrict__ TVc_l, const float2* __restrict__ w64c_l,
    unsigned short* __restrict__ y)
{
    __shared__ __align__(16) unsigned short uT[BLK * UTP];   // 9.2 KB
    __shared__ __align__(16) unsigned short ST[BLK * UTP];   // 9.2 KB
    __shared__ float INC[BLK * INP];                         // 16.9 KB
    const int t = threadIdx.x;
    const int wv = t >> 6, lane = t & 63;
    const int lanei = lane & 15, quad = lane >> 4;
    const int h = blockIdx.x >> 3, ct = blockIdx.x & 7;      // ct = batch
    const float* ub = u + (size_t)(ct * H + h) * L;

    {   // stage uT[col=blk][j] bf16
        int col = t >> 2, q = t & 3;
#pragma unroll
        for (int i = 0; i < 4; ++i) {
            float4 v = *(const float4*)(ub + col * 64 + q * 16 + i * 4);
            ushort4 o4;
            o4.x = f2bf(v.x); o4.y = f2bf(v.y); o4.z = f2bf(v.z); o4.w = f2bf(v.w);
            *(ushort4*)&uT[col * UTP + q * 16 + i * 4] = o4;
        }
    }
    __syncthreads();

    // ---- GEMM-A: INC[blk][k] = sum_j M[k][j] * u[blk*64+j] ----
    {
        f32x4 acc[4];
#pragma unroll
        for (int nt = 0; nt < 4; ++nt) acc[nt] = (f32x4){0.f, 0.f, 0.f, 0.f};
        const unsigned short* arow = Mm_l + (size_t)h * BLK * MJP + (wv * 16 + lanei) * MJP + quad * 8;
#pragma unroll
        for (int kt = 0; kt < 2; ++kt) {
            short8 a8 = *(const short8*)(arow + kt * 32);
#pragma unroll
            for (int nt = 0; nt < 4; ++nt) {
                short8 b8 = *(const short8*)&uT[(nt * 16 + lanei) * UTP + kt * 32 + quad * 8];
                acc[nt] = __builtin_amdgcn_mfma_f32_16x16x32_bf16(a8, b8, acc[nt], 0, 0, 0);
            }
        }
#pragma unroll
        for (int nt = 0; nt < 4; ++nt) {
            int col = nt * 16 + lanei;
            int k0 = wv * 16 + quad * 4;
#pragma unroll
            for (int reg = 0; reg < 4; ++reg)
                INC[col * INP + k0 + reg] = acc[nt][reg];
        }
    }
    __syncthreads();

    // ---- chain: wave 0, lane n<32; prefix states -> ST bf16 ----
    if (wv == 0 && lane < 32) {
        const int n = lane;
        const float2 w64 = w64c_l[h * N2 + n];
        float sr = 0.f, si = 0.f;
#pragma unroll 8
        for (int blk = 0; blk < NBLK; ++blk) {
            ST[blk * UTP + n]      = f2bf(sr);
            ST[blk * UTP + 32 + n] = f2bf(si);
            float ir = INC[blk * INP + n];
            float ii = INC[blk * INP + 32 + n];
            float nr = fmaf(w64.x, sr, fmaf(-w64.y, si, ir));
            float ni = fmaf(w64.x, si, fmaf(w64.y, sr, ii));
            sr = nr; si = ni;
        }
    }
    __syncthreads();

    // ---- GEMM-B: y = gelu(T*U + Vc*S), store bf16 ----
    {
        f32x4 acc[4];
#pragma unroll
        for (int nt = 0; nt < 4; ++nt) acc[nt] = (f32x4){0.f, 0.f, 0.f, 0.f};
        const unsigned short* arow = TVc_l + (size_t)h * BLK * TVP + (wv * 16 + lanei) * TVP + quad * 8;
#pragma unroll
        for (int kt = 0; kt < 4; ++kt) {
            short8 a8 = *(const short8*)(arow + kt * 32);
            const unsigned short* bb = (kt < 2) ? uT : ST;
            int ko = (kt & 1) * 32 + quad * 8;
#pragma unroll
            for (int nt = 0; nt < 4; ++nt) {
                short8 b8 = *(const short8*)&bb[(nt * 16 + lanei) * UTP + ko];
                acc[nt] = __builtin_amdgcn_mfma_f32_16x16x32_bf16(a8, b8, acc[nt], 0, 0, 0);
            }
        }
        unsigned short* yb = y + (size_t)(ct * H + h) * L;
#pragma unroll
        for (int nt = 0; nt < 4; ++nt) {
            int blk = nt * 16 + lanei;
            int i0 = wv * 16 + quad * 4;
            ushort4 o4;
            o4.x = f2bf(gelu_f(acc[nt][0]));
            o4.y = f2bf(gelu_f(acc[nt][1]));
            o4.z = f2bf(gelu_f(acc[nt][2]));
            o4.w = f2bf(gelu_f(acc[nt][3]));
            *(ushort4*)(yb + blk * 64 + i0) = o4;
        }
    }
}

// ---------------- MFMA GEMM(512x256 @ 256x32) + bias + GLU + residual + channel-LN ----------------
__global__ __launch_bounds__(256) void k_gemm(
    const unsigned short* __restrict__ y, float* __restrict__ u,
    const unsigned short* __restrict__ Wb, const float* __restrict__ bo,
    const float* __restrict__ lng, const float* __restrict__ lnb)
{
    __shared__ __align__(16) unsigned short yS[32 * YPAD];
    __shared__ float bS[O2];
    __shared__ float lgS[H], lbS[H];
    __shared__ float redS[4][2][16], redQ[4][2][16];

    const int t = threadIdx.x;
    const int wv = t >> 6;
    const int lane = t & 63;
    const int lanei = lane & 15;
    const int quad = lane >> 4;
    const int bid = blockIdx.x;
    const int b = bid >> 7;
    const int l0 = (bid & 127) * TL;

    // residual prefetch (independent of LDS) — overlaps MFMA below
    float* ub = u + (size_t)b * H * L + l0;
    float res[4][2][4];
#pragma unroll
    for (int j = 0; j < 4; ++j) {
        int orow = wv * 64 + j * 16 + quad * 4;
#pragma unroll
        for (int nt = 0; nt < 2; ++nt) {
            int lc = nt * 16 + lanei;
#pragma unroll
            for (int reg = 0; reg < 4; ++reg)
                res[j][nt][reg] = ub[(size_t)(orow + reg) * L + lc];
        }
    }

    {   // stage bf16 y tile -> yS[l][h]
        const int i = t & 3, hr = t >> 2;   // i: l-group of 8, hr: 0..63
        const unsigned short* yb = y + (size_t)b * H * L + l0 + i * 8;
#pragma unroll
        for (int ps = 0; ps < 4; ++ps) {
            int h = ps * 64 + hr;
            short8 v8 = *(const short8*)(yb + (size_t)h * L);
#pragma unroll
            for (int r = 0; r < 8; ++r)
                yS[(i * 8 + r) * YPAD + h] = (unsigned short)v8[r];
        }
        for (int idx = t; idx < O2; idx += 256) bS[idx] = bo[idx];
        lgS[t & 255] = lng[t & 255];
        lbS[t & 255] = lnb[t & 255];
    }
    __syncthreads();

    f32x4 acc[2][4][2];
#pragma unroll
    for (int p = 0; p < 2; ++p)
#pragma unroll
        for (int j = 0; j < 4; ++j)
#pragma unroll
            for (int nt = 0; nt < 2; ++nt)
                acc[p][j][nt] = (f32x4){0.f, 0.f, 0.f, 0.f};

    size_t abase[2][4];
#pragma unroll
    for (int p = 0; p < 2; ++p)
#pragma unroll
        for (int j = 0; j < 4; ++j) {
            int o = p * 256 + wv * 64 + j * 16 + lanei;
            abase[p][j] = (size_t)o * H + quad * 8;
        }

#pragma unroll
    for (int kt = 0; kt < 8; ++kt) {
        short8 bfr[2];
#pragma unroll
        for (int nt = 0; nt < 2; ++nt)
            bfr[nt] = *(const short8*)&yS[(nt * 16 + lanei) * YPAD + kt * 32 + quad * 8];
#pragma unroll
        for (int p = 0; p < 2; ++p)
#pragma unroll
            for (int j = 0; j < 4; ++j) {
                short8 a8 = *(const short8*)(Wb + abase[p][j] + kt * 32);
#pragma unroll
                for (int nt = 0; nt < 2; ++nt)
                    acc[p][j][nt] = __builtin_amdgcn_mfma_f32_16x16x32_bf16(
                        a8, bfr[nt], acc[p][j][nt], 0, 0, 0);
            }
    }

    float psum[2] = {0.f, 0.f}, psq[2] = {0.f, 0.f};
#pragma unroll
    for (int j = 0; j < 4; ++j) {
#pragma unroll
        for (int nt = 0; nt < 2; ++nt) {
#pragma unroll
            for (int reg = 0; reg < 4; ++reg) {
                int o = wv * 64 + j * 16 + quad * 4 + reg;
                float a = acc[0][j][nt][reg] + bS[o];
                float g = acc[1][j][nt][reg] + bS[o + 256];
                float glu = a / (1.f + expf(-g));
                float val = glu + res[j][nt][reg];
                acc[0][j][nt][reg] = val;
                psum[nt] += val;
                psq[nt] = fmaf(val, val, psq[nt]);
            }
        }
    }
#pragma unroll
    for (int nt = 0; nt < 2; ++nt) {
        psum[nt] += __shfl_xor(psum[nt], 16);
        psum[nt] += __shfl_xor(psum[nt], 32);
        psq[nt]  += __shfl_xor(psq[nt], 16);
        psq[nt]  += __shfl_xor(psq[nt], 32);
    }
    if (lane < 16) {
#pragma unroll
        for (int nt = 0; nt < 2; ++nt) {
            redS[wv][nt][lanei] = psum[nt];
            redQ[wv][nt][lanei] = psq[nt];
        }
    }
    __syncthreads();
    float mcol[2], icol[2];
#pragma unroll
    for (int nt = 0; nt < 2; ++nt) {
        float s = redS[0][nt][lanei] + redS[1][nt][lanei] + redS[2][nt][lanei] + redS[3][nt][lanei];
        float q = redQ[0][nt][lanei] + redQ[1][nt][lanei] + redQ[2][nt][lanei] + redQ[3][nt][lanei];
        float m = s * (1.0f / 256.0f);
        float v = q * (1.0f / 256.0f) - m * m;
        mcol[nt] = m;
        icol[nt] = rsqrtf(v + 1e-5f);
    }
#pragma unroll
    for (int j = 0; j < 4; ++j) {
        int orow = wv * 64 + j * 16 + quad * 4;
#pragma unroll
        for (int nt = 0; nt < 2; ++nt) {
            int lc = nt * 16 + lanei;
#pragma unroll
            for (int reg = 0; reg < 4; ++reg) {
                int o = orow + reg;
                float val = acc[0][j][nt][reg];
                float ov = (val - mcol[nt]) * icol[nt] * lgS[o] + lbS[o];
                ub[(size_t)o * L + lc] = ov;
            }
        }
    }
}

extern "C" void kernel_launch(void* const* d_in, const int* in_sizes, int n_in,
                              void* d_out, int out_size, void* d_ws, size_t ws_size,
                              hipStream_t stream)
{
    const float* x      = (const float*)d_in[0];
    const float* log_dt = (const float*)d_in[1];
    const float* log_Ar = (const float*)d_in[2];
    const float* A_im   = (const float*)d_in[3];
    const float* C_re   = (const float*)d_in[4];
    const float* C_im   = (const float*)d_in[5];
    const float* Dv     = (const float*)d_in[6];
    const float* Wout   = (const float*)d_in[7];
    const float* bout   = (const float*)d_in[8];
    const float* lng    = (const float*)d_in[9];
    const float* lnb    = (const float*)d_in[10];
    float* out = (float*)d_out;

    float* u           = (float*)d_ws;                              // 33.5 MB
    unsigned short* Wb = (unsigned short*)(u + (size_t)B * H * L);  // 1 MB
    float4* prm        = (float4*)(Wb + (size_t)NL * O2 * H);       // 0.5 MB
    unsigned short* TVc = (unsigned short*)(prm + (size_t)NL * H * N2);   // 17.8 MB
    unsigned short* Mm  = TVc + (size_t)NL * H * BLK * TVP;               // 9.4 MB
    float2* w64c       = (float2*)(Mm + (size_t)NL * H * BLK * MJP);      // 0.26 MB
    unsigned short* y  = (unsigned short*)out;   // bf16 y aliases d_out (dead before k_tr_uo)

    k_prm<<<(NL * H * N2 + 255) / 256, 256, 0, stream>>>(log_dt, log_Ar, A_im, C_re, C_im, prm);
    k_wcvt<<<NL * O2 * H / 1024, 256, 0, stream>>>(Wout, Wb);
    k_mats<<<NL * H / 2, 64, 0, stream>>>(prm, Dv, TVc, Mm, w64c);
    k_tr_xu<<<dim3(8, 128, B), 256, 0, stream>>>(x, u);
    for (int layer = 0; layer < NL; ++layer) {
        k_scan3<<<H * 8, 256, 0, stream>>>(u, Mm + (size_t)layer * H * BLK * MJP,
                                           TVc + (size_t)layer * H * BLK * TVP,
                                           w64c + (size_t)layer * H * N2, y);
        k_gemm<<<B * L / TL, 256, 0, stream>>>(y, u, Wb + (size_t)layer * O2 * H,
                                               bout + layer * O2, lng + layer * H, lnb + layer * H);
    }
    k_tr_uo<<<dim3(8, 128, B), 256, 0, stream>>>(u, out);
}

// Round 6
// 355.258 us; speedup vs baseline: 5.9821x; 1.3287x over previous
//
#include <hip/hip_runtime.h>
#include <math.h>

#define B    8
#define L    4096
#define H    256
#define N2   32
#define NL   4
#define O2   512   // 2H
#define BLK  64    // scan block length
#define NBLK 64    // L/BLK
#define TVP  136   // TVc row stride (elems): 64 T + 64 Vc + 8 pad
#define MJP  72    // Mm row stride
#define UTP  72    // uT/ST LDS row stride (u16)
#define INP  66    // INC LDS row stride (f32)
#define TL2  64    // k_gemm l-tile
#define YPAD 264   // k_gemm yS row stride (u16)

typedef __attribute__((ext_vector_type(8))) short short8;
typedef __attribute__((ext_vector_type(4))) float f32x4;

__device__ __forceinline__ unsigned short f2bf(float f)
{
    unsigned int u = __float_as_uint(f);
    unsigned int r = (u + 0x7fffu + ((u >> 16) & 1u)) >> 16;
    return (unsigned short)r;
}

__device__ __forceinline__ float bf2f(unsigned short v)
{
    return __uint_as_float(((unsigned int)v) << 16);
}

__device__ __forceinline__ float gelu_f(float x)
{
    return 0.5f * x * (1.0f + erff(x * 0.70710678118654752f));
}

// ---------------- per-(layer,h,n) params: w = exp(dt*A), cm2 = 2*C*(w-1)/A ----------------
__global__ __launch_bounds__(256) void k_prm(
    const float* __restrict__ log_dt, const float* __restrict__ log_Ar,
    const float* __restrict__ A_im, const float* __restrict__ C_re,
    const float* __restrict__ C_im, float4* __restrict__ prm)
{
    int idx = blockIdx.x * 256 + threadIdx.x;     // NL*H*N2 = 32768
    if (idx >= NL * H * N2) return;
    int layer = idx / (H * N2);
    int rem = idx - layer * (H * N2);
    int h = rem / N2;
    double dt = exp((double)log_dt[layer * H + h]);
    double Ar = -exp((double)log_Ar[idx]);
    double Ai = (double)A_im[idx];
    double dtr = dt * Ar, dti = dt * Ai;
    double er = exp(dtr);
    double wr = er * cos(dti), wi = er * sin(dti);
    double numr = wr - 1.0, numi = wi;
    double den = Ar * Ar + Ai * Ai;
    double qr = (numr * Ar + numi * Ai) / den;
    double qi = (numi * Ar - numr * Ai) / den;
    double cr = (double)C_re[idx], ci = (double)C_im[idx];
    double cmr = cr * qr - ci * qi;
    double cmi = cr * qi + ci * qr;
    prm[idx] = make_float4((float)wr, (float)wi, (float)(2.0 * cmr), (float)(2.0 * cmi));
}

// ---------------- build per-(layer,h) matrices: T|Vc (64x136), M (64x72), w^64 ----------------
__global__ __launch_bounds__(64) void k_mats(
    const float4* __restrict__ prm, const float* __restrict__ Dv,
    unsigned short* __restrict__ TVc, unsigned short* __restrict__ Mm,
    float2* __restrict__ w64c)
{
    __shared__ float kb[2][BLK];
    const int t = threadIdx.x;
    const int g = t >> 5, n = t & 31;
    const int id = blockIdx.x * 2 + g;       // NL*H ids
    const int layer = id >> 8, h = id & 255;
    const float4 p = prm[(layer * H + h) * N2 + n];
    const float wr = p.x, wi = p.y, cr = p.z, ci = p.w;
    const float Dh = Dv[layer * H + h];
    unsigned short* tv = TVc + (size_t)(layer * H + h) * BLK * TVP;
    unsigned short* mm = Mm + (size_t)(layer * H + h) * BLK * MJP;
    float vr = 1.f, vi = 0.f;                // w^0
    for (int d = 0; d < BLK; ++d) {
        float pk = fmaf(cr, vr, -(ci * vi));
        pk += __shfl_xor(pk, 1);  pk += __shfl_xor(pk, 2);
        pk += __shfl_xor(pk, 4);  pk += __shfl_xor(pk, 8);
        pk += __shfl_xor(pk, 16);
        if (n == 0) kb[g][d] = pk;
        mm[n * MJP + (63 - d)]        = f2bf(vr);
        mm[(32 + n) * MJP + (63 - d)] = f2bf(vi);
        float nvr = vr * wr - vi * wi;
        float nvi = vr * wi + vi * wr;
        vr = nvr; vi = nvi;
        float qr = fmaf(cr, vr, -(ci * vi));
        float qi = fmaf(cr, vi, ci * vr);
        tv[d * TVP + 64 + n] = f2bf(qr);
        tv[d * TVP + 96 + n] = f2bf(-qi);
    }
    w64c[(layer * H + h) * N2 + n] = make_float2(vr, vi);
    __syncthreads();
    for (int i = 0; i < BLK; ++i) {
#pragma unroll
        for (int hf = 0; hf < 2; ++hf) {
            int j = n + hf * 32;
            float val = (j > i) ? 0.f : ((j == i) ? (kb[g][0] + Dh) : kb[g][i - j]);
            tv[i * TVP + j] = f2bf(val);
        }
    }
}

// ---------------- transpose x (B,L,H) fp32 -> u (B,H,L) bf16 ----------------
__global__ __launch_bounds__(256) void k_tr_xu(const float* __restrict__ x, unsigned short* __restrict__ u)
{
    __shared__ float t[32][33];
    int b = blockIdx.z;
    int h0 = blockIdx.x * 32, l0 = blockIdx.y * 32;
    int tx = threadIdx.x & 31, ty = threadIdx.x >> 5;
    const float* xb = x + (size_t)b * L * H;
    unsigned short* ub = u + (size_t)b * H * L;
#pragma unroll
    for (int i = 0; i < 4; ++i)
        t[ty + i * 8][tx] = xb[(size_t)(l0 + ty + i * 8) * H + h0 + tx];
    __syncthreads();
#pragma unroll
    for (int i = 0; i < 4; ++i)
        ub[(size_t)(h0 + ty + i * 8) * L + l0 + tx] = f2bf(t[tx][ty + i * 8]);
}

// ---------------- transpose u (B,H,L) bf16 -> out (B,L,H) fp32 ----------------
__global__ __launch_bounds__(256) void k_tr_uo(const unsigned short* __restrict__ u, float* __restrict__ o)
{
    __shared__ float t[32][33];
    int b = blockIdx.z;
    int h0 = blockIdx.x * 32, l0 = blockIdx.y * 32;
    int tx = threadIdx.x & 31, ty = threadIdx.x >> 5;
    const unsigned short* ub = u + (size_t)b * H * L;
    float* ob = o + (size_t)b * L * H;
#pragma unroll
    for (int i = 0; i < 4; ++i)
        t[ty + i * 8][tx] = bf2f(ub[(size_t)(h0 + ty + i * 8) * L + l0 + tx]);
    __syncthreads();
#pragma unroll
    for (int i = 0; i < 4; ++i)
        ob[(size_t)(l0 + ty + i * 8) * H + h0 + tx] = t[tx][ty + i * 8];
}

// ---------------- Wout fp32 -> bf16 ----------------
__global__ __launch_bounds__(256) void k_wcvt(const float* __restrict__ w, unsigned short* __restrict__ wb)
{
    int idx = (blockIdx.x * 256 + threadIdx.x) * 4;   // NL*O2*H = 524288
    float4 v = *(const float4*)(w + idx);
    ushort4 o;
    o.x = f2bf(v.x); o.y = f2bf(v.y); o.z = f2bf(v.z); o.w = f2bf(v.w);
    *(ushort4*)(wb + idx) = o;
}

// ---------------- fused scan: GEMM-A + chain + GEMM-B, all in LDS; y out bf16 ----------------
__global__ __launch_bounds__(256) void k_scan3(
    const unsigned short* __restrict__ u, const unsigned short* __restrict__ Mm_l,
    const unsigned short* __restrict__ TVc_l, const float2* __restrict__ w64c_l,
    unsigned short* __restrict__ y)
{
    __shared__ __align__(16) unsigned short uT[BLK * UTP];   // 9.2 KB
    __shared__ __align__(16) unsigned short ST[BLK * UTP];   // 9.2 KB
    __shared__ float INC[BLK * INP];                         // 16.9 KB
    const int t = threadIdx.x;
    const int wv = t >> 6, lane = t & 63;
    const int lanei = lane & 15, quad = lane >> 4;
    const int h = blockIdx.x >> 3, ct = blockIdx.x & 7;      // ct = batch
    const unsigned short* ub = u + (size_t)(ct * H + h) * L;

    {   // stage uT[col=blk][j] bf16 (direct copy)
        int col = t >> 2, q = t & 3;
        *(short8*)&uT[col * UTP + q * 16]     = *(const short8*)(ub + col * 64 + q * 16);
        *(short8*)&uT[col * UTP + q * 16 + 8] = *(const short8*)(ub + col * 64 + q * 16 + 8);
    }
    __syncthreads();

    // ---- GEMM-A: INC[blk][k] = sum_j M[k][j] * u[blk*64+j] ----
    {
        f32x4 acc[4];
#pragma unroll
        for (int nt = 0; nt < 4; ++nt) acc[nt] = (f32x4){0.f, 0.f, 0.f, 0.f};
        const unsigned short* arow = Mm_l + (size_t)h * BLK * MJP + (wv * 16 + lanei) * MJP + quad * 8;
#pragma unroll
        for (int kt = 0; kt < 2; ++kt) {
            short8 a8 = *(const short8*)(arow + kt * 32);
#pragma unroll
            for (int nt = 0; nt < 4; ++nt) {
                short8 b8 = *(const short8*)&uT[(nt * 16 + lanei) * UTP + kt * 32 + quad * 8];
                acc[nt] = __builtin_amdgcn_mfma_f32_16x16x32_bf16(a8, b8, acc[nt], 0, 0, 0);
            }
        }
#pragma unroll
        for (int nt = 0; nt < 4; ++nt) {
            int col = nt * 16 + lanei;
            int k0 = wv * 16 + quad * 4;
#pragma unroll
            for (int reg = 0; reg < 4; ++reg)
                INC[col * INP + k0 + reg] = acc[nt][reg];
        }
    }
    __syncthreads();

    // ---- chain: wave 0, lane n<32; prefix states -> ST bf16 ----
    if (wv == 0 && lane < 32) {
        const int n = lane;
        const float2 w64 = w64c_l[h * N2 + n];
        float sr = 0.f, si = 0.f;
#pragma unroll 8
        for (int blk = 0; blk < NBLK; ++blk) {
            ST[blk * UTP + n]      = f2bf(sr);
            ST[blk * UTP + 32 + n] = f2bf(si);
            float ir = INC[blk * INP + n];
            float ii = INC[blk * INP + 32 + n];
            float nr = fmaf(w64.x, sr, fmaf(-w64.y, si, ir));
            float ni = fmaf(w64.x, si, fmaf(w64.y, sr, ii));
            sr = nr; si = ni;
        }
    }
    __syncthreads();

    // ---- GEMM-B: y = gelu(T*U + Vc*S), store bf16 ----
    {
        f32x4 acc[4];
#pragma unroll
        for (int nt = 0; nt < 4; ++nt) acc[nt] = (f32x4){0.f, 0.f, 0.f, 0.f};
        const unsigned short* arow = TVc_l + (size_t)h * BLK * TVP + (wv * 16 + lanei) * TVP + quad * 8;
#pragma unroll
        for (int kt = 0; kt < 4; ++kt) {
            short8 a8 = *(const short8*)(arow + kt * 32);
            const unsigned short* bb = (kt < 2) ? uT : ST;
            int ko = (kt & 1) * 32 + quad * 8;
#pragma unroll
            for (int nt = 0; nt < 4; ++nt) {
                short8 b8 = *(const short8*)&bb[(nt * 16 + lanei) * UTP + ko];
                acc[nt] = __builtin_amdgcn_mfma_f32_16x16x32_bf16(a8, b8, acc[nt], 0, 0, 0);
            }
        }
        unsigned short* yb = y + (size_t)(ct * H + h) * L;
#pragma unroll
        for (int nt = 0; nt < 4; ++nt) {
            int blk = nt * 16 + lanei;
            int i0 = wv * 16 + quad * 4;
            ushort4 o4;
            o4.x = f2bf(gelu_f(acc[nt][0]));
            o4.y = f2bf(gelu_f(acc[nt][1]));
            o4.z = f2bf(gelu_f(acc[nt][2]));
            o4.w = f2bf(gelu_f(acc[nt][3]));
            *(ushort4*)(yb + blk * 64 + i0) = o4;
        }
    }
}

// ---------------- MFMA GEMM(512x256 @ 256x64) + bias + GLU + residual(bf16) + channel-LN ----------------
// 512 threads, 8 waves; wave wv covers o in [wv*32, wv*32+32) paired with [256+wv*32, ...).
__global__ __launch_bounds__(512, 4) void k_gemm(
    const unsigned short* __restrict__ y, unsigned short* __restrict__ u,
    const unsigned short* __restrict__ Wb, const float* __restrict__ bo,
    const float* __restrict__ lng, const float* __restrict__ lnb)
{
    __shared__ __align__(16) unsigned short yS[TL2 * YPAD];   // 33.8 KB
    __shared__ float bS[O2];
    __shared__ float lgS[H], lbS[H];
    __shared__ float redS[8][4][16], redQ[8][4][16];

    const int t = threadIdx.x;
    const int wv = t >> 6;
    const int lane = t & 63;
    const int lanei = lane & 15;
    const int quad = lane >> 4;
    const int b = blockIdx.x >> 6;           // L/TL2 = 64 tiles per batch
    const int l0 = (blockIdx.x & 63) * TL2;

    {   // stage y tile (256h x 64l bf16) -> yS[l][h ^ 8*(l>>3)] (swizzled, conflict-free-ish)
        const int i = t & 7, hr = t >> 3;    // i: l-octet 0..7, hr: 0..63
        const unsigned short* yb = y + (size_t)b * H * L + l0 + i * 8;
#pragma unroll
        for (int ps = 0; ps < 4; ++ps) {
            int h = ps * 64 + hr;
            short8 v8 = *(const short8*)(yb + (size_t)h * L);
#pragma unroll
            for (int r = 0; r < 8; ++r)
                yS[(i * 8 + r) * YPAD + (h ^ (8 * i))] = (unsigned short)v8[r];
        }
        if (t < O2) bS[t] = bo[t];
        if (t < H) { lgS[t] = lng[t]; lbS[t] = lnb[t]; }
    }
    __syncthreads();

    f32x4 acc[2][2][4];
#pragma unroll
    for (int p = 0; p < 2; ++p)
#pragma unroll
        for (int jj = 0; jj < 2; ++jj)
#pragma unroll
            for (int nt = 0; nt < 4; ++nt)
                acc[p][jj][nt] = (f32x4){0.f, 0.f, 0.f, 0.f};

    size_t abase[2][2];
#pragma unroll
    for (int p = 0; p < 2; ++p)
#pragma unroll
        for (int jj = 0; jj < 2; ++jj)
            abase[p][jj] = (size_t)(p * 256 + wv * 32 + jj * 16 + lanei) * H + quad * 8;

#pragma unroll
    for (int kt = 0; kt < 8; ++kt) {
        short8 bfr[4];
#pragma unroll
        for (int nt = 0; nt < 4; ++nt) {
            int lp = nt * 16 + lanei;
            int a = (2 * nt + (lanei >> 3)) & 7;
            bfr[nt] = *(const short8*)&yS[lp * YPAD + ((kt * 32 + quad * 8) ^ (8 * a))];
        }
#pragma unroll
        for (int p = 0; p < 2; ++p)
#pragma unroll
            for (int jj = 0; jj < 2; ++jj) {
                short8 a8 = *(const short8*)(Wb + abase[p][jj] + kt * 32);
#pragma unroll
                for (int nt = 0; nt < 4; ++nt)
                    acc[p][jj][nt] = __builtin_amdgcn_mfma_f32_16x16x32_bf16(
                        a8, bfr[nt], acc[p][jj][nt], 0, 0, 0);
            }
    }

    // ---- epilogue: bias + GLU + residual(bf16); LN stats ----
    float psum[4] = {0.f, 0.f, 0.f, 0.f}, psq[4] = {0.f, 0.f, 0.f, 0.f};
    unsigned short* ub = u + (size_t)b * H * L + l0;
#pragma unroll
    for (int jj = 0; jj < 2; ++jj) {
#pragma unroll
        for (int nt = 0; nt < 4; ++nt) {
            int lc = nt * 16 + lanei;
#pragma unroll
            for (int reg = 0; reg < 4; ++reg) {
                int o = wv * 32 + jj * 16 + quad * 4 + reg;
                float a = acc[0][jj][nt][reg] + bS[o];
                float g = acc[1][jj][nt][reg] + bS[o + 256];
                float glu = a / (1.f + expf(-g));
                float val = glu + bf2f(ub[(size_t)o * L + lc]);
                acc[0][jj][nt][reg] = val;
                psum[nt] += val;
                psq[nt] = fmaf(val, val, psq[nt]);
            }
        }
    }
#pragma unroll
    for (int nt = 0; nt < 4; ++nt) {
        psum[nt] += __shfl_xor(psum[nt], 16);
        psum[nt] += __shfl_xor(psum[nt], 32);
        psq[nt]  += __shfl_xor(psq[nt], 16);
        psq[nt]  += __shfl_xor(psq[nt], 32);
    }
    if (lane < 16) {
#pragma unroll
        for (int nt = 0; nt < 4; ++nt) {
            redS[wv][nt][lanei] = psum[nt];
            redQ[wv][nt][lanei] = psq[nt];
        }
    }
    __syncthreads();
    float mcol[4], icol[4];
#pragma unroll
    for (int nt = 0; nt < 4; ++nt) {
        float s = 0.f, q = 0.f;
#pragma unroll
        for (int w = 0; w < 8; ++w) { s += redS[w][nt][lanei]; q += redQ[w][nt][lanei]; }
        float m = s * (1.0f / 256.0f);
        float v = q * (1.0f / 256.0f) - m * m;
        mcol[nt] = m;
        icol[nt] = rsqrtf(v + 1e-5f);
    }
#pragma unroll
    for (int jj = 0; jj < 2; ++jj) {
#pragma unroll
        for (int nt = 0; nt < 4; ++nt) {
            int lc = nt * 16 + lanei;
#pragma unroll
            for (int reg = 0; reg < 4; ++reg) {
                int o = wv * 32 + jj * 16 + quad * 4 + reg;
                float val = acc[0][jj][nt][reg];
                float ov = (val - mcol[nt]) * icol[nt] * lgS[o] + lbS[o];
                ub[(size_t)o * L + lc] = f2bf(ov);
            }
        }
    }
}

extern "C" void kernel_launch(void* const* d_in, const int* in_sizes, int n_in,
                              void* d_out, int out_size, void* d_ws, size_t ws_size,
                              hipStream_t stream)
{
    const float* x      = (const float*)d_in[0];
    const float* log_dt = (const float*)d_in[1];
    const float* log_Ar = (const float*)d_in[2];
    const float* A_im   = (const float*)d_in[3];
    const float* C_re   = (const float*)d_in[4];
    const float* C_im   = (const float*)d_in[5];
    const float* Dv     = (const float*)d_in[6];
    const float* Wout   = (const float*)d_in[7];
    const float* bout   = (const float*)d_in[8];
    const float* lng    = (const float*)d_in[9];
    const float* lnb    = (const float*)d_in[10];
    float* out = (float*)d_out;

    unsigned short* u  = (unsigned short*)d_ws;                     // B*H*L bf16 (16.8 MB)
    unsigned short* Wb = u + (size_t)B * H * L;                     // 1 MB
    float4* prm        = (float4*)(Wb + (size_t)NL * O2 * H);       // 0.5 MB
    unsigned short* TVc = (unsigned short*)(prm + (size_t)NL * H * N2);   // 17.8 MB
    unsigned short* Mm  = TVc + (size_t)NL * H * BLK * TVP;               // 9.4 MB
    float2* w64c       = (float2*)(Mm + (size_t)NL * H * BLK * MJP);      // 0.26 MB
    unsigned short* y  = (unsigned short*)out;   // bf16 y aliases d_out (dead before k_tr_uo)

    k_prm<<<(NL * H * N2 + 255) / 256, 256, 0, stream>>>(log_dt, log_Ar, A_im, C_re, C_im, prm);
    k_wcvt<<<NL * O2 * H / 1024, 256, 0, stream>>>(Wout, Wb);
    k_mats<<<NL * H / 2, 64, 0, stream>>>(prm, Dv, TVc, Mm, w64c);
    k_tr_xu<<<dim3(8, 128, B), 256, 0, stream>>>(x, u);
    for (int layer = 0; layer < NL; ++layer) {
        k_scan3<<<H * 8, 256, 0, stream>>>(u, Mm + (size_t)layer * H * BLK * MJP,
                                           TVc + (size_t)layer * H * BLK * TVP,
                                           w64c + (size_t)layer * H * N2, y);
        k_gemm<<<B * L / TL2, 512, 0, stream>>>(y, u, Wb + (size_t)layer * O2 * H,
                                                bout + layer * O2, lng + layer * H, lnb + layer * H);
    }
    k_tr_uo<<<dim3(8, 128, B), 256, 0, stream>>>(u, out);
}

// Round 7
// 344.339 us; speedup vs baseline: 6.1718x; 1.0317x over previous
//
#include <hip/hip_runtime.h>
#include <math.h>

#define B    8
#define L    4096
#define H    256
#define N2   32
#define NL   4
#define O2   512   // 2H
#define BLK  64    // scan block length
#define NBLK 64    // L/BLK
#define TVP  136   // TVc row stride (elems): 64 T + 64 Vc + 8 pad
#define MJP  72    // Mm row stride
#define UTP  72    // uT/ST LDS row stride (u16)
#define INP  66    // INC LDS row stride (f32)
#define TL2  64    // k_gemm l-tile
#define YPAD 264   // k_gemm yS row stride (u16)
#define USP  72    // k_gemm uS row stride (u16)

typedef __attribute__((ext_vector_type(8))) short short8;
typedef __attribute__((ext_vector_type(4))) float f32x4;

__device__ __forceinline__ unsigned short f2bf(float f)
{
    unsigned int u = __float_as_uint(f);
    unsigned int r = (u + 0x7fffu + ((u >> 16) & 1u)) >> 16;
    return (unsigned short)r;
}

__device__ __forceinline__ float bf2f(unsigned short v)
{
    return __uint_as_float(((unsigned int)v) << 16);
}

__device__ __forceinline__ float gelu_f(float x)
{
    return 0.5f * x * (1.0f + erff(x * 0.70710678118654752f));
}

// ---------------- build per-(layer,h): params (inline double) + T|Vc + M + w^64 ----------------
__global__ __launch_bounds__(64) void k_mats(
    const float* __restrict__ log_dt, const float* __restrict__ log_Ar,
    const float* __restrict__ A_im, const float* __restrict__ C_re,
    const float* __restrict__ C_im, const float* __restrict__ Dv,
    unsigned short* __restrict__ TVc, unsigned short* __restrict__ Mm,
    float2* __restrict__ w64c)
{
    __shared__ float kb[2][BLK];
    const int t = threadIdx.x;
    const int g = t >> 5, n = t & 31;
    const int id = blockIdx.x * 2 + g;       // NL*H ids
    const int layer = id >> 8, h = id & 255;
    const int idx = (layer * H + h) * N2 + n;
    // inline per-(layer,h,n) param computation (double)
    double dt = exp((double)log_dt[layer * H + h]);
    double Ar = -exp((double)log_Ar[idx]);
    double Ai = (double)A_im[idx];
    double dtr = dt * Ar, dti = dt * Ai;
    double er = exp(dtr);
    double dwr = er * cos(dti), dwi = er * sin(dti);
    double numr = dwr - 1.0, numi = dwi;
    double den = Ar * Ar + Ai * Ai;
    double qr0 = (numr * Ar + numi * Ai) / den;
    double qi0 = (numi * Ar - numr * Ai) / den;
    double dcr = (double)C_re[idx], dci = (double)C_im[idx];
    const float wr = (float)dwr, wi = (float)dwi;
    const float cr = (float)(2.0 * (dcr * qr0 - dci * qi0));
    const float ci = (float)(2.0 * (dcr * qi0 + dci * qr0));
    const float Dh = Dv[layer * H + h];
    unsigned short* tv = TVc + (size_t)(layer * H + h) * BLK * TVP;
    unsigned short* mm = Mm + (size_t)(layer * H + h) * BLK * MJP;
    float vr = 1.f, vi = 0.f;                // w^0
    for (int d = 0; d < BLK; ++d) {
        float pk = fmaf(cr, vr, -(ci * vi));
        pk += __shfl_xor(pk, 1);  pk += __shfl_xor(pk, 2);
        pk += __shfl_xor(pk, 4);  pk += __shfl_xor(pk, 8);
        pk += __shfl_xor(pk, 16);
        if (n == 0) kb[g][d] = pk;
        mm[n * MJP + (63 - d)]        = f2bf(vr);
        mm[(32 + n) * MJP + (63 - d)] = f2bf(vi);
        float nvr = vr * wr - vi * wi;
        float nvi = vr * wi + vi * wr;
        vr = nvr; vi = nvi;
        float qr = fmaf(cr, vr, -(ci * vi));
        float qi = fmaf(cr, vi, ci * vr);
        tv[d * TVP + 64 + n] = f2bf(qr);
        tv[d * TVP + 96 + n] = f2bf(-qi);
    }
    w64c[(layer * H + h) * N2 + n] = make_float2(vr, vi);
    __syncthreads();
    for (int i = 0; i < BLK; ++i) {
#pragma unroll
        for (int hf = 0; hf < 2; ++hf) {
            int j = n + hf * 32;
            float val = (j > i) ? 0.f : ((j == i) ? (kb[g][0] + Dh) : kb[g][i - j]);
            tv[i * TVP + j] = f2bf(val);
        }
    }
}

// ---------------- transpose x (B,L,H) fp32 -> u (B,H,L) bf16 ----------------
__global__ __launch_bounds__(256) void k_tr_xu(const float* __restrict__ x, unsigned short* __restrict__ u)
{
    __shared__ float t[32][33];
    int b = blockIdx.z;
    int h0 = blockIdx.x * 32, l0 = blockIdx.y * 32;
    int tx = threadIdx.x & 31, ty = threadIdx.x >> 5;
    const float* xb = x + (size_t)b * L * H;
    unsigned short* ub = u + (size_t)b * H * L;
#pragma unroll
    for (int i = 0; i < 4; ++i)
        t[ty + i * 8][tx] = xb[(size_t)(l0 + ty + i * 8) * H + h0 + tx];
    __syncthreads();
#pragma unroll
    for (int i = 0; i < 4; ++i)
        ub[(size_t)(h0 + ty + i * 8) * L + l0 + tx] = f2bf(t[tx][ty + i * 8]);
}

// ---------------- Wout fp32 -> bf16 ----------------
__global__ __launch_bounds__(256) void k_wcvt(const float* __restrict__ w, unsigned short* __restrict__ wb)
{
    int idx = (blockIdx.x * 256 + threadIdx.x) * 4;   // NL*O2*H = 524288
    float4 v = *(const float4*)(w + idx);
    ushort4 o;
    o.x = f2bf(v.x); o.y = f2bf(v.y); o.z = f2bf(v.z); o.w = f2bf(v.w);
    *(ushort4*)(wb + idx) = o;
}

// ---------------- fused scan: GEMM-A + 2-level chain + GEMM-B, all in LDS; y out bf16 ----------------
__global__ __launch_bounds__(256) void k_scan3(
    const unsigned short* __restrict__ u, const unsigned short* __restrict__ Mm_l,
    const unsigned short* __restrict__ TVc_l, const float2* __restrict__ w64c_l,
    unsigned short* __restrict__ y)
{
    __shared__ __align__(16) unsigned short uT[BLK * UTP];   // 9.2 KB
    __shared__ __align__(16) unsigned short ST[BLK * UTP];   // 9.2 KB
    __shared__ float INC[BLK * INP];                         // 16.9 KB
    __shared__ float2 cLd[4][32];
    const int t = threadIdx.x;
    const int wv = t >> 6, lane = t & 63;
    const int lanei = lane & 15, quad = lane >> 4;
    const int h = blockIdx.x >> 3, ct = blockIdx.x & 7;      // ct = batch
    const unsigned short* ub = u + (size_t)(ct * H + h) * L;

    {   // stage uT[col=blk][j] bf16 (direct copy)
        int col = t >> 2, q = t & 3;
        *(short8*)&uT[col * UTP + q * 16]     = *(const short8*)(ub + col * 64 + q * 16);
        *(short8*)&uT[col * UTP + q * 16 + 8] = *(const short8*)(ub + col * 64 + q * 16 + 8);
    }
    __syncthreads();

    // ---- GEMM-A: INC[blk][k] = sum_j M[k][j] * u[blk*64+j] ----
    {
        f32x4 acc[4];
#pragma unroll
        for (int nt = 0; nt < 4; ++nt) acc[nt] = (f32x4){0.f, 0.f, 0.f, 0.f};
        const unsigned short* arow = Mm_l + (size_t)h * BLK * MJP + (wv * 16 + lanei) * MJP + quad * 8;
#pragma unroll
        for (int kt = 0; kt < 2; ++kt) {
            short8 a8 = *(const short8*)(arow + kt * 32);
#pragma unroll
            for (int nt = 0; nt < 4; ++nt) {
                short8 b8 = *(const short8*)&uT[(nt * 16 + lanei) * UTP + kt * 32 + quad * 8];
                acc[nt] = __builtin_amdgcn_mfma_f32_16x16x32_bf16(a8, b8, acc[nt], 0, 0, 0);
            }
        }
#pragma unroll
        for (int nt = 0; nt < 4; ++nt) {
            int col = nt * 16 + lanei;
            int k0 = wv * 16 + quad * 4;
#pragma unroll
            for (int reg = 0; reg < 4; ++reg)
                INC[col * INP + k0 + reg] = acc[nt][reg];
        }
    }
    __syncthreads();

    // ---- chain: two-level parallel scan (each wave owns 16 blocks) ----
    {
        const int n = lane & 31;
        float Pr[16], Pi[16];
        float w1r = 1.f, w1i = 0.f;
        float2 w64 = make_float2(0.f, 0.f);
        if (lane < 32) {
            w64 = w64c_l[h * N2 + n];
            float sr = 0.f, si = 0.f;
            const int base = wv * 16;
#pragma unroll
            for (int k = 0; k < 16; ++k) {
                Pr[k] = sr; Pi[k] = si;
                float ir = INC[(base + k) * INP + n];
                float ii = INC[(base + k) * INP + 32 + n];
                float nr = fmaf(w64.x, sr, fmaf(-w64.y, si, ir));
                float ni = fmaf(w64.x, si, fmaf(w64.y, sr, ii));
                sr = nr; si = ni;
            }
            cLd[wv][n] = make_float2(sr, si);
            // w1024 = w64^16 via 4 squarings
            float ar = w64.x, ai = w64.y;
#pragma unroll
            for (int q = 0; q < 4; ++q) {
                float nr2 = ar * ar - ai * ai;
                float ni2 = 2.f * ar * ai;
                ar = nr2; ai = ni2;
            }
            w1r = ar; w1i = ai;
        }
        __syncthreads();
        if (lane < 32) {
            float Cr = 0.f, Ci = 0.f;
            for (int wp = 0; wp < wv; ++wp) {
                float2 Lw = cLd[wp][n];
                float nr = fmaf(w1r, Cr, fmaf(-w1i, Ci, Lw.x));
                float ni = fmaf(w1r, Ci, fmaf(w1i, Cr, Lw.y));
                Cr = nr; Ci = ni;
            }
            float pr = 1.f, pi = 0.f;
#pragma unroll
            for (int k = 0; k < 16; ++k) {
                int blk = wv * 16 + k;
                float Sr = fmaf(pr, Cr, fmaf(-pi, Ci, Pr[k]));
                float Si = fmaf(pr, Ci, fmaf(pi, Cr, Pi[k]));
                ST[blk * UTP + n]      = f2bf(Sr);
                ST[blk * UTP + 32 + n] = f2bf(Si);
                float npr = pr * w64.x - pi * w64.y;
                float npi = pr * w64.y + pi * w64.x;
                pr = npr; pi = npi;
            }
        }
    }
    __syncthreads();

    // ---- GEMM-B: y = gelu(T*U + Vc*S), store bf16 ----
    {
        f32x4 acc[4];
#pragma unroll
        for (int nt = 0; nt < 4; ++nt) acc[nt] = (f32x4){0.f, 0.f, 0.f, 0.f};
        const unsigned short* arow = TVc_l + (size_t)h * BLK * TVP + (wv * 16 + lanei) * TVP + quad * 8;
#pragma unroll
        for (int kt = 0; kt < 4; ++kt) {
            short8 a8 = *(const short8*)(arow + kt * 32);
            const unsigned short* bb = (kt < 2) ? uT : ST;
            int ko = (kt & 1) * 32 + quad * 8;
#pragma unroll
            for (int nt = 0; nt < 4; ++nt) {
                short8 b8 = *(const short8*)&bb[(nt * 16 + lanei) * UTP + ko];
                acc[nt] = __builtin_amdgcn_mfma_f32_16x16x32_bf16(a8, b8, acc[nt], 0, 0, 0);
            }
        }
        unsigned short* yb = y + (size_t)(ct * H + h) * L;
#pragma unroll
        for (int nt = 0; nt < 4; ++nt) {
            int blk = nt * 16 + lanei;
            int i0 = wv * 16 + quad * 4;
            ushort4 o4;
            o4.x = f2bf(gelu_f(acc[nt][0]));
            o4.y = f2bf(gelu_f(acc[nt][1]));
            o4.z = f2bf(gelu_f(acc[nt][2]));
            o4.w = f2bf(gelu_f(acc[nt][3]));
            *(ushort4*)(yb + blk * 64 + i0) = o4;
        }
    }
}

// ---------------- MFMA GEMM(512x256 @ 256x64) + bias + GLU + residual(LDS) + channel-LN ----------------
// 512 threads, 8 waves; wave wv covers o in [wv*32, wv*32+32) paired with [256+wv*32, ...).
// outp == nullptr: write bf16 u in-place. outp != nullptr (final layer): write fp32 (B,L,H) out.
__global__ __launch_bounds__(512, 4) void k_gemm(
    const unsigned short* __restrict__ y, unsigned short* __restrict__ u,
    const unsigned short* __restrict__ Wb, const float* __restrict__ bo,
    const float* __restrict__ lng, const float* __restrict__ lnb,
    float* __restrict__ outp)
{
    __shared__ __align__(16) unsigned short yS[TL2 * YPAD];   // 33.8 KB
    __shared__ __align__(16) unsigned short uS[H * USP];      // 36.9 KB
    __shared__ float bS[O2];
    __shared__ float lgS[H], lbS[H];
    __shared__ float redS[8][4][16], redQ[8][4][16];

    const int t = threadIdx.x;
    const int wv = t >> 6;
    const int lane = t & 63;
    const int lanei = lane & 15;
    const int quad = lane >> 4;
    const int b = blockIdx.x >> 6;           // L/TL2 = 64 tiles per batch
    const int l0 = (blockIdx.x & 63) * TL2;

    unsigned short* ub = u + (size_t)b * H * L + l0;
    {   // stage y tile (swizzled transpose) + residual u tile (row-major) + consts
        const int i = t & 7, hr = t >> 3;    // i: l-octet 0..7, hr: 0..63
        const unsigned short* yb = y + (size_t)b * H * L + l0 + i * 8;
#pragma unroll
        for (int ps = 0; ps < 4; ++ps) {
            int h = ps * 64 + hr;
            short8 v8 = *(const short8*)(yb + (size_t)h * L);
            short8 r8 = *(const short8*)(ub + (size_t)h * L + i * 8);
            *(short8*)&uS[h * USP + i * 8] = r8;
#pragma unroll
            for (int r = 0; r < 8; ++r)
                yS[(i * 8 + r) * YPAD + (h ^ (8 * i))] = (unsigned short)v8[r];
        }
        if (t < O2) bS[t] = bo[t];
        if (t < H) { lgS[t] = lng[t]; lbS[t] = lnb[t]; }
    }
    __syncthreads();

    f32x4 acc[2][2][4];
#pragma unroll
    for (int p = 0; p < 2; ++p)
#pragma unroll
        for (int jj = 0; jj < 2; ++jj)
#pragma unroll
            for (int nt = 0; nt < 4; ++nt)
                acc[p][jj][nt] = (f32x4){0.f, 0.f, 0.f, 0.f};

    size_t abase[2][2];
#pragma unroll
    for (int p = 0; p < 2; ++p)
#pragma unroll
        for (int jj = 0; jj < 2; ++jj)
            abase[p][jj] = (size_t)(p * 256 + wv * 32 + jj * 16 + lanei) * H + quad * 8;

#pragma unroll
    for (int kt = 0; kt < 8; ++kt) {
        short8 bfr[4];
#pragma unroll
        for (int nt = 0; nt < 4; ++nt) {
            int lp = nt * 16 + lanei;
            int a = (2 * nt + (lanei >> 3)) & 7;
            bfr[nt] = *(const short8*)&yS[lp * YPAD + ((kt * 32 + quad * 8) ^ (8 * a))];
        }
#pragma unroll
        for (int p = 0; p < 2; ++p)
#pragma unroll
            for (int jj = 0; jj < 2; ++jj) {
                short8 a8 = *(const short8*)(Wb + abase[p][jj] + kt * 32);
#pragma unroll
                for (int nt = 0; nt < 4; ++nt)
                    acc[p][jj][nt] = __builtin_amdgcn_mfma_f32_16x16x32_bf16(
                        a8, bfr[nt], acc[p][jj][nt], 0, 0, 0);
            }
    }

    // ---- epilogue: bias + GLU + residual(LDS); LN stats ----
    float psum[4] = {0.f, 0.f, 0.f, 0.f}, psq[4] = {0.f, 0.f, 0.f, 0.f};
#pragma unroll
    for (int jj = 0; jj < 2; ++jj) {
#pragma unroll
        for (int nt = 0; nt < 4; ++nt) {
            int lc = nt * 16 + lanei;
#pragma unroll
            for (int reg = 0; reg < 4; ++reg) {
                int o = wv * 32 + jj * 16 + quad * 4 + reg;
                float a = acc[0][jj][nt][reg] + bS[o];
                float g = acc[1][jj][nt][reg] + bS[o + 256];
                float glu = a / (1.f + expf(-g));
                float val = glu + bf2f(uS[o * USP + lc]);
                acc[0][jj][nt][reg] = val;
                psum[nt] += val;
                psq[nt] = fmaf(val, val, psq[nt]);
            }
        }
    }
#pragma unroll
    for (int nt = 0; nt < 4; ++nt) {
        psum[nt] += __shfl_xor(psum[nt], 16);
        psum[nt] += __shfl_xor(psum[nt], 32);
        psq[nt]  += __shfl_xor(psq[nt], 16);
        psq[nt]  += __shfl_xor(psq[nt], 32);
    }
    if (lane < 16) {
#pragma unroll
        for (int nt = 0; nt < 4; ++nt) {
            redS[wv][nt][lanei] = psum[nt];
            redQ[wv][nt][lanei] = psq[nt];
        }
    }
    __syncthreads();
    float mcol[4], icol[4];
#pragma unroll
    for (int nt = 0; nt < 4; ++nt) {
        float s = 0.f, q = 0.f;
#pragma unroll
        for (int w = 0; w < 8; ++w) { s += redS[w][nt][lanei]; q += redQ[w][nt][lanei]; }
        float m = s * (1.0f / 256.0f);
        float v = q * (1.0f / 256.0f) - m * m;
        mcol[nt] = m;
        icol[nt] = rsqrtf(v + 1e-5f);
    }
    if (outp == nullptr) {
#pragma unroll
        for (int jj = 0; jj < 2; ++jj) {
#pragma unroll
            for (int nt = 0; nt < 4; ++nt) {
                int lc = nt * 16 + lanei;
#pragma unroll
                for (int reg = 0; reg < 4; ++reg) {
                    int o = wv * 32 + jj * 16 + quad * 4 + reg;
                    float val = acc[0][jj][nt][reg];
                    float ov = (val - mcol[nt]) * icol[nt] * lgS[o] + lbS[o];
                    ub[(size_t)o * L + lc] = f2bf(ov);
                }
            }
        }
    } else {
        // final layer: write fp32 transposed out (B,L,H) directly
#pragma unroll
        for (int jj = 0; jj < 2; ++jj) {
#pragma unroll
            for (int nt = 0; nt < 4; ++nt) {
                int lc = nt * 16 + lanei;
                int o0 = wv * 32 + jj * 16 + quad * 4;
                float4 ov;
#pragma unroll
                for (int reg = 0; reg < 4; ++reg) {
                    int o = o0 + reg;
                    float val = acc[0][jj][nt][reg];
                    ((float*)&ov)[reg] = (val - mcol[nt]) * icol[nt] * lgS[o] + lbS[o];
                }
                *(float4*)(outp + ((size_t)b * L + l0 + lc) * H + o0) = ov;
            }
        }
    }
}

extern "C" void kernel_launch(void* const* d_in, const int* in_sizes, int n_in,
                              void* d_out, int out_size, void* d_ws, size_t ws_size,
                              hipStream_t stream)
{
    const float* x      = (const float*)d_in[0];
    const float* log_dt = (const float*)d_in[1];
    const float* log_Ar = (const float*)d_in[2];
    const float* A_im   = (const float*)d_in[3];
    const float* C_re   = (const float*)d_in[4];
    const float* C_im   = (const float*)d_in[5];
    const float* Dv     = (const float*)d_in[6];
    const float* Wout   = (const float*)d_in[7];
    const float* bout   = (const float*)d_in[8];
    const float* lng    = (const float*)d_in[9];
    const float* lnb    = (const float*)d_in[10];
    float* out = (float*)d_out;

    unsigned short* u   = (unsigned short*)d_ws;                          // 16.8 MB
    unsigned short* Wb  = u + (size_t)B * H * L;                          // 1 MB
    unsigned short* TVc = Wb + (size_t)NL * O2 * H;                       // 17.8 MB
    unsigned short* Mm  = TVc + (size_t)NL * H * BLK * TVP;               // 9.4 MB
    float2* w64c        = (float2*)(Mm + (size_t)NL * H * BLK * MJP);     // 0.26 MB
    unsigned short* y   = (unsigned short*)(w64c + (size_t)NL * H * N2);  // 16.8 MB

    k_wcvt<<<NL * O2 * H / 1024, 256, 0, stream>>>(Wout, Wb);
    k_mats<<<NL * H / 2, 64, 0, stream>>>(log_dt, log_Ar, A_im, C_re, C_im, Dv, TVc, Mm, w64c);
    k_tr_xu<<<dim3(8, 128, B), 256, 0, stream>>>(x, u);
    for (int layer = 0; layer < NL; ++layer) {
        k_scan3<<<H * 8, 256, 0, stream>>>(u, Mm + (size_t)layer * H * BLK * MJP,
                                           TVc + (size_t)layer * H * BLK * TVP,
                                           w64c + (size_t)layer * H * N2, y);
        k_gemm<<<B * L / TL2, 512, 0, stream>>>(y, u, Wb + (size_t)layer * O2 * H,
                                                bout + layer * O2, lng + layer * H, lnb + layer * H,
                                                (layer == NL - 1) ? out : nullptr);
    }
}

// Round 8
// 321.408 us; speedup vs baseline: 6.6121x; 1.0713x over previous
//
#include <hip/hip_runtime.h>
#include <math.h>

#define B    8
#define L    4096
#define H    256
#define N2   32
#define NL   4
#define O2   512   // 2H
#define BLK  64    // scan block length
#define NBLK 64    // L/BLK
#define TVP  136   // TVc row stride (elems): 64 T + 64 Vc + 8 pad
#define MJP  72    // Mm row stride
#define UTP  72    // uT/ST LDS row stride (u16)
#define INP  66    // INC LDS row stride (f32)
#define TL2  64    // k_gemm l-tile
#define YPAD 264   // k_gemm yS row stride (u16)

typedef __attribute__((ext_vector_type(8))) short short8;
typedef __attribute__((ext_vector_type(4))) float f32x4;

__device__ __forceinline__ unsigned short f2bf(float f)
{
    unsigned int u = __float_as_uint(f);
    unsigned int r = (u + 0x7fffu + ((u >> 16) & 1u)) >> 16;
    return (unsigned short)r;
}

__device__ __forceinline__ float bf2f(unsigned short v)
{
    return __uint_as_float(((unsigned int)v) << 16);
}

// fast GELU: x * sigmoid(1.5957691216(x + 0.044715 x^3)) — max err ~2e-3, OK vs 0.1175 threshold
__device__ __forceinline__ float gelu_f(float x)
{
    float t = 1.59576912161f * fmaf(0.044715f * x * x, x, x);
    return x / (1.f + __expf(-t));
}

// ---------------- build per-(layer,h): params (inline double) + T|Vc + M + w^64 ----------------
__global__ __launch_bounds__(64) void k_mats(
    const float* __restrict__ log_dt, const float* __restrict__ log_Ar,
    const float* __restrict__ A_im, const float* __restrict__ C_re,
    const float* __restrict__ C_im, const float* __restrict__ Dv,
    unsigned short* __restrict__ TVc, unsigned short* __restrict__ Mm,
    float2* __restrict__ w64c)
{
    __shared__ float kb[2][BLK];
    const int t = threadIdx.x;
    const int g = t >> 5, n = t & 31;
    const int id = blockIdx.x * 2 + g;       // NL*H ids
    const int layer = id >> 8, h = id & 255;
    const int idx = (layer * H + h) * N2 + n;
    double dt = exp((double)log_dt[layer * H + h]);
    double Ar = -exp((double)log_Ar[idx]);
    double Ai = (double)A_im[idx];
    double dtr = dt * Ar, dti = dt * Ai;
    double er = exp(dtr);
    double dwr = er * cos(dti), dwi = er * sin(dti);
    double numr = dwr - 1.0, numi = dwi;
    double den = Ar * Ar + Ai * Ai;
    double qr0 = (numr * Ar + numi * Ai) / den;
    double qi0 = (numi * Ar - numr * Ai) / den;
    double dcr = (double)C_re[idx], dci = (double)C_im[idx];
    const float wr = (float)dwr, wi = (float)dwi;
    const float cr = (float)(2.0 * (dcr * qr0 - dci * qi0));
    const float ci = (float)(2.0 * (dcr * qi0 + dci * qr0));
    const float Dh = Dv[layer * H + h];
    unsigned short* tv = TVc + (size_t)(layer * H + h) * BLK * TVP;
    unsigned short* mm = Mm + (size_t)(layer * H + h) * BLK * MJP;
    float vr = 1.f, vi = 0.f;                // w^0
    for (int d = 0; d < BLK; ++d) {
        float pk = fmaf(cr, vr, -(ci * vi));
        pk += __shfl_xor(pk, 1);  pk += __shfl_xor(pk, 2);
        pk += __shfl_xor(pk, 4);  pk += __shfl_xor(pk, 8);
        pk += __shfl_xor(pk, 16);
        if (n == 0) kb[g][d] = pk;
        mm[n * MJP + (63 - d)]        = f2bf(vr);
        mm[(32 + n) * MJP + (63 - d)] = f2bf(vi);
        float nvr = vr * wr - vi * wi;
        float nvi = vr * wi + vi * wr;
        vr = nvr; vi = nvi;
        float qr = fmaf(cr, vr, -(ci * vi));
        float qi = fmaf(cr, vi, ci * vr);
        tv[d * TVP + 64 + n] = f2bf(qr);
        tv[d * TVP + 96 + n] = f2bf(-qi);
    }
    w64c[(layer * H + h) * N2 + n] = make_float2(vr, vi);
    __syncthreads();
    for (int i = 0; i < BLK; ++i) {
#pragma unroll
        for (int hf = 0; hf < 2; ++hf) {
            int j = n + hf * 32;
            float val = (j > i) ? 0.f : ((j == i) ? (kb[g][0] + Dh) : kb[g][i - j]);
            tv[i * TVP + j] = f2bf(val);
        }
    }
}

// ---------------- transpose x (B,L,H) fp32 -> u (B,H,L) bf16 ----------------
__global__ __launch_bounds__(256) void k_tr_xu(const float* __restrict__ x, unsigned short* __restrict__ u)
{
    __shared__ float t[32][33];
    int b = blockIdx.z;
    int h0 = blockIdx.x * 32, l0 = blockIdx.y * 32;
    int tx = threadIdx.x & 31, ty = threadIdx.x >> 5;
    const float* xb = x + (size_t)b * L * H;
    unsigned short* ub = u + (size_t)b * H * L;
#pragma unroll
    for (int i = 0; i < 4; ++i)
        t[ty + i * 8][tx] = xb[(size_t)(l0 + ty + i * 8) * H + h0 + tx];
    __syncthreads();
#pragma unroll
    for (int i = 0; i < 4; ++i)
        ub[(size_t)(h0 + ty + i * 8) * L + l0 + tx] = f2bf(t[tx][ty + i * 8]);
}

// ---------------- Wout fp32 -> bf16 ----------------
__global__ __launch_bounds__(256) void k_wcvt(const float* __restrict__ w, unsigned short* __restrict__ wb)
{
    int idx = (blockIdx.x * 256 + threadIdx.x) * 4;   // NL*O2*H = 524288
    float4 v = *(const float4*)(w + idx);
    ushort4 o;
    o.x = f2bf(v.x); o.y = f2bf(v.y); o.z = f2bf(v.z); o.w = f2bf(v.w);
    *(ushort4*)(wb + idx) = o;
}

// ---------------- fused scan: GEMM-A + 2-level chain + GEMM-B, all in LDS; y out bf16 ----------------
__global__ __launch_bounds__(256) void k_scan3(
    const unsigned short* __restrict__ u, const unsigned short* __restrict__ Mm_l,
    const unsigned short* __restrict__ TVc_l, const float2* __restrict__ w64c_l,
    unsigned short* __restrict__ y)
{
    __shared__ __align__(16) unsigned short uT[BLK * UTP];   // 9.2 KB
    __shared__ __align__(16) unsigned short ST[BLK * UTP];   // 9.2 KB
    __shared__ float INC[BLK * INP];                         // 16.9 KB
    __shared__ float2 cLd[4][32];
    const int t = threadIdx.x;
    const int wv = t >> 6, lane = t & 63;
    const int lanei = lane & 15, quad = lane >> 4;
    const int h = blockIdx.x >> 3, ct = blockIdx.x & 7;      // ct = batch
    const unsigned short* ub = u + (size_t)(ct * H + h) * L;

    {   // stage uT[col=blk][j] bf16 (direct copy)
        int col = t >> 2, q = t & 3;
        *(short8*)&uT[col * UTP + q * 16]     = *(const short8*)(ub + col * 64 + q * 16);
        *(short8*)&uT[col * UTP + q * 16 + 8] = *(const short8*)(ub + col * 64 + q * 16 + 8);
    }
    __syncthreads();

    // ---- GEMM-A: INC[blk][k] = sum_j M[k][j] * u[blk*64+j] ----
    {
        f32x4 acc[4];
#pragma unroll
        for (int nt = 0; nt < 4; ++nt) acc[nt] = (f32x4){0.f, 0.f, 0.f, 0.f};
        const unsigned short* arow = Mm_l + (size_t)h * BLK * MJP + (wv * 16 + lanei) * MJP + quad * 8;
#pragma unroll
        for (int kt = 0; kt < 2; ++kt) {
            short8 a8 = *(const short8*)(arow + kt * 32);
#pragma unroll
            for (int nt = 0; nt < 4; ++nt) {
                short8 b8 = *(const short8*)&uT[(nt * 16 + lanei) * UTP + kt * 32 + quad * 8];
                acc[nt] = __builtin_amdgcn_mfma_f32_16x16x32_bf16(a8, b8, acc[nt], 0, 0, 0);
            }
        }
#pragma unroll
        for (int nt = 0; nt < 4; ++nt) {
            int col = nt * 16 + lanei;
            int k0 = wv * 16 + quad * 4;
#pragma unroll
            for (int reg = 0; reg < 4; ++reg)
                INC[col * INP + k0 + reg] = acc[nt][reg];
        }
    }
    __syncthreads();

    // ---- chain: two-level parallel scan (each wave owns 16 blocks) ----
    {
        const int n = lane & 31;
        float Pr[16], Pi[16];
        float w1r = 1.f, w1i = 0.f;
        float2 w64 = make_float2(0.f, 0.f);
        if (lane < 32) {
            w64 = w64c_l[h * N2 + n];
            float sr = 0.f, si = 0.f;
            const int base = wv * 16;
#pragma unroll
            for (int k = 0; k < 16; ++k) {
                Pr[k] = sr; Pi[k] = si;
                float ir = INC[(base + k) * INP + n];
                float ii = INC[(base + k) * INP + 32 + n];
                float nr = fmaf(w64.x, sr, fmaf(-w64.y, si, ir));
                float ni = fmaf(w64.x, si, fmaf(w64.y, sr, ii));
                sr = nr; si = ni;
            }
            cLd[wv][n] = make_float2(sr, si);
            float ar = w64.x, ai = w64.y;
#pragma unroll
            for (int q = 0; q < 4; ++q) {
                float nr2 = ar * ar - ai * ai;
                float ni2 = 2.f * ar * ai;
                ar = nr2; ai = ni2;
            }
            w1r = ar; w1i = ai;
        }
        __syncthreads();
        if (lane < 32) {
            float Cr = 0.f, Ci = 0.f;
            for (int wp = 0; wp < wv; ++wp) {
                float2 Lw = cLd[wp][n];
                float nr = fmaf(w1r, Cr, fmaf(-w1i, Ci, Lw.x));
                float ni = fmaf(w1r, Ci, fmaf(w1i, Cr, Lw.y));
                Cr = nr; Ci = ni;
            }
            float pr = 1.f, pi = 0.f;
#pragma unroll
            for (int k = 0; k < 16; ++k) {
                int blk = wv * 16 + k;
                float Sr = fmaf(pr, Cr, fmaf(-pi, Ci, Pr[k]));
                float Si = fmaf(pr, Ci, fmaf(pi, Cr, Pi[k]));
                ST[blk * UTP + n]      = f2bf(Sr);
                ST[blk * UTP + 32 + n] = f2bf(Si);
                float npr = pr * w64.x - pi * w64.y;
                float npi = pr * w64.y + pi * w64.x;
                pr = npr; pi = npi;
            }
        }
    }
    __syncthreads();

    // ---- GEMM-B: y = gelu(T*U + Vc*S), store bf16 ----
    {
        f32x4 acc[4];
#pragma unroll
        for (int nt = 0; nt < 4; ++nt) acc[nt] = (f32x4){0.f, 0.f, 0.f, 0.f};
        const unsigned short* arow = TVc_l + (size_t)h * BLK * TVP + (wv * 16 + lanei) * TVP + quad * 8;
#pragma unroll
        for (int kt = 0; kt < 4; ++kt) {
            short8 a8 = *(const short8*)(arow + kt * 32);
            const unsigned short* bb = (kt < 2) ? uT : ST;
            int ko = (kt & 1) * 32 + quad * 8;
#pragma unroll
            for (int nt = 0; nt < 4; ++nt) {
                short8 b8 = *(const short8*)&bb[(nt * 16 + lanei) * UTP + ko];
                acc[nt] = __builtin_amdgcn_mfma_f32_16x16x32_bf16(a8, b8, acc[nt], 0, 0, 0);
            }
        }
        unsigned short* yb = y + (size_t)(ct * H + h) * L;
#pragma unroll
        for (int nt = 0; nt < 4; ++nt) {
            int blk = nt * 16 + lanei;
            int i0 = wv * 16 + quad * 4;
            ushort4 o4;
            o4.x = f2bf(gelu_f(acc[nt][0]));
            o4.y = f2bf(gelu_f(acc[nt][1]));
            o4.z = f2bf(gelu_f(acc[nt][2]));
            o4.w = f2bf(gelu_f(acc[nt][3]));
            *(ushort4*)(yb + blk * 64 + i0) = o4;
        }
    }
}

// ---------------- MFMA GEMM(512x256 @ 256x64) + bias + GLU + residual(bf16) + channel-LN ----------------
// outp == nullptr: write bf16 u in-place. outp != nullptr (final layer): write fp32 (B,L,H) out.
__global__ __launch_bounds__(512, 4) void k_gemm(
    const unsigned short* __restrict__ y, unsigned short* __restrict__ u,
    const unsigned short* __restrict__ Wb, const float* __restrict__ bo,
    const float* __restrict__ lng, const float* __restrict__ lnb,
    float* __restrict__ outp)
{
    __shared__ __align__(16) unsigned short yS[TL2 * YPAD];   // 33.8 KB
    __shared__ float bS[O2];
    __shared__ float lgS[H], lbS[H];
    __shared__ float redS[8][4][16], redQ[8][4][16];

    const int t = threadIdx.x;
    const int wv = t >> 6;
    const int lane = t & 63;
    const int lanei = lane & 15;
    const int quad = lane >> 4;
    const int b = blockIdx.x >> 6;           // L/TL2 = 64 tiles per batch
    const int l0 = (blockIdx.x & 63) * TL2;

    {   // stage y tile (256h x 64l bf16) -> yS[l][h ^ 8*(l>>3)] (swizzled)
        const int i = t & 7, hr = t >> 3;    // i: l-octet 0..7, hr: 0..63
        const unsigned short* yb = y + (size_t)b * H * L + l0 + i * 8;
#pragma unroll
        for (int ps = 0; ps < 4; ++ps) {
            int h = ps * 64 + hr;
            short8 v8 = *(const short8*)(yb + (size_t)h * L);
#pragma unroll
            for (int r = 0; r < 8; ++r)
                yS[(i * 8 + r) * YPAD + (h ^ (8 * i))] = (unsigned short)v8[r];
        }
        if (t < O2) bS[t] = bo[t];
        if (t < H) { lgS[t] = lng[t]; lbS[t] = lnb[t]; }
    }
    __syncthreads();

    f32x4 acc[2][2][4];
#pragma unroll
    for (int p = 0; p < 2; ++p)
#pragma unroll
        for (int jj = 0; jj < 2; ++jj)
#pragma unroll
            for (int nt = 0; nt < 4; ++nt)
                acc[p][jj][nt] = (f32x4){0.f, 0.f, 0.f, 0.f};

    size_t abase[2][2];
#pragma unroll
    for (int p = 0; p < 2; ++p)
#pragma unroll
        for (int jj = 0; jj < 2; ++jj)
            abase[p][jj] = (size_t)(p * 256 + wv * 32 + jj * 16 + lanei) * H + quad * 8;

#pragma unroll
    for (int kt = 0; kt < 8; ++kt) {
        short8 bfr[4];
#pragma unroll
        for (int nt = 0; nt < 4; ++nt) {
            int lp = nt * 16 + lanei;
            int a = (2 * nt + (lanei >> 3)) & 7;
            bfr[nt] = *(const short8*)&yS[lp * YPAD + ((kt * 32 + quad * 8) ^ (8 * a))];
        }
#pragma unroll
        for (int p = 0; p < 2; ++p)
#pragma unroll
            for (int jj = 0; jj < 2; ++jj) {
                short8 a8 = *(const short8*)(Wb + abase[p][jj] + kt * 32);
#pragma unroll
                for (int nt = 0; nt < 4; ++nt)
                    acc[p][jj][nt] = __builtin_amdgcn_mfma_f32_16x16x32_bf16(
                        a8, bfr[nt], acc[p][jj][nt], 0, 0, 0);
            }
    }

    // ---- epilogue: bias + GLU + residual(bf16 scalar loads); LN stats ----
    float psum[4] = {0.f, 0.f, 0.f, 0.f}, psq[4] = {0.f, 0.f, 0.f, 0.f};
    unsigned short* ub = u + (size_t)b * H * L + l0;
#pragma unroll
    for (int jj = 0; jj < 2; ++jj) {
#pragma unroll
        for (int nt = 0; nt < 4; ++nt) {
            int lc = nt * 16 + lanei;
#pragma unroll
            for (int reg = 0; reg < 4; ++reg) {
                int o = wv * 32 + jj * 16 + quad * 4 + reg;
                float a = acc[0][jj][nt][reg] + bS[o];
                float g = acc[1][jj][nt][reg] + bS[o + 256];
                float glu = a / (1.f + __expf(-g));
                float val = glu + bf2f(ub[(size_t)o * L + lc]);
                acc[0][jj][nt][reg] = val;
                psum[nt] += val;
                psq[nt] = fmaf(val, val, psq[nt]);
            }
        }
    }
#pragma unroll
    for (int nt = 0; nt < 4; ++nt) {
        psum[nt] += __shfl_xor(psum[nt], 16);
        psum[nt] += __shfl_xor(psum[nt], 32);
        psq[nt]  += __shfl_xor(psq[nt], 16);
        psq[nt]  += __shfl_xor(psq[nt], 32);
    }
    if (lane < 16) {
#pragma unroll
        for (int nt = 0; nt < 4; ++nt) {
            redS[wv][nt][lanei] = psum[nt];
            redQ[wv][nt][lanei] = psq[nt];
        }
    }
    __syncthreads();
    float mcol[4], icol[4];
#pragma unroll
    for (int nt = 0; nt < 4; ++nt) {
        float s = 0.f, q = 0.f;
#pragma unroll
        for (int w = 0; w < 8; ++w) { s += redS[w][nt][lanei]; q += redQ[w][nt][lanei]; }
        float m = s * (1.0f / 256.0f);
        float v = q * (1.0f / 256.0f) - m * m;
        mcol[nt] = m;
        icol[nt] = rsqrtf(v + 1e-5f);
    }
    if (outp == nullptr) {
#pragma unroll
        for (int jj = 0; jj < 2; ++jj) {
#pragma unroll
            for (int nt = 0; nt < 4; ++nt) {
                int lc = nt * 16 + lanei;
#pragma unroll
                for (int reg = 0; reg < 4; ++reg) {
                    int o = wv * 32 + jj * 16 + quad * 4 + reg;
                    float val = acc[0][jj][nt][reg];
                    float ov = (val - mcol[nt]) * icol[nt] * lgS[o] + lbS[o];
                    ub[(size_t)o * L + lc] = f2bf(ov);
                }
            }
        }
    } else {
        // final layer: write fp32 transposed out (B,L,H) directly
#pragma unroll
        for (int jj = 0; jj < 2; ++jj) {
#pragma unroll
            for (int nt = 0; nt < 4; ++nt) {
                int lc = nt * 16 + lanei;
                int o0 = wv * 32 + jj * 16 + quad * 4;
                float4 ov;
#pragma unroll
                for (int reg = 0; reg < 4; ++reg) {
                    int o = o0 + reg;
                    float val = acc[0][jj][nt][reg];
                    ((float*)&ov)[reg] = (val - mcol[nt]) * icol[nt] * lgS[o] + lbS[o];
                }
                *(float4*)(outp + ((size_t)b * L + l0 + lc) * H + o0) = ov;
            }
        }
    }
}

extern "C" void kernel_launch(void* const* d_in, const int* in_sizes, int n_in,
                              void* d_out, int out_size, void* d_ws, size_t ws_size,
                              hipStream_t stream)
{
    const float* x      = (const float*)d_in[0];
    const float* log_dt = (const float*)d_in[1];
    const float* log_Ar = (const float*)d_in[2];
    const float* A_im   = (const float*)d_in[3];
    const float* C_re   = (const float*)d_in[4];
    const float* C_im   = (const float*)d_in[5];
    const float* Dv     = (const float*)d_in[6];
    const float* Wout   = (const float*)d_in[7];
    const float* bout   = (const float*)d_in[8];
    const float* lng    = (const float*)d_in[9];
    const float* lnb    = (const float*)d_in[10];
    float* out = (float*)d_out;

    unsigned short* u   = (unsigned short*)d_ws;                          // 16.8 MB
    unsigned short* Wb  = u + (size_t)B * H * L;                          // 1 MB
    unsigned short* TVc = Wb + (size_t)NL * O2 * H;                       // 17.8 MB
    unsigned short* Mm  = TVc + (size_t)NL * H * BLK * TVP;               // 9.4 MB
    float2* w64c        = (float2*)(Mm + (size_t)NL * H * BLK * MJP);     // 0.26 MB
    unsigned short* y   = (unsigned short*)(w64c + (size_t)NL * H * N2);  // 16.8 MB

    k_wcvt<<<NL * O2 * H / 1024, 256, 0, stream>>>(Wout, Wb);
    k_mats<<<NL * H / 2, 64, 0, stream>>>(log_dt, log_Ar, A_im, C_re, C_im, Dv, TVc, Mm, w64c);
    k_tr_xu<<<dim3(8, 128, B), 256, 0, stream>>>(x, u);
    for (int layer = 0; layer < NL; ++layer) {
        k_scan3<<<H * 8, 256, 0, stream>>>(u, Mm + (size_t)layer * H * BLK * MJP,
                                           TVc + (size_t)layer * H * BLK * TVP,
                                           w64c + (size_t)layer * H * N2, y);
        k_gemm<<<B * L / TL2, 512, 0, stream>>>(y, u, Wb + (size_t)layer * O2 * H,
                                                bout + layer * O2, lng + layer * H, lnb + layer * H,
                                                (layer == NL - 1) ? out : nullptr);
    }
}